// Round 1
// baseline (4385.558 us; speedup 1.0000x reference)
//
#include <hip/hip_runtime.h>

#define N_NODES 50000
#define N_EDGES 800000

// ---------------------------------------------------------------------------
// Register-blocked f32 GEMM: C[M,N] = A[M,K] @ B[K,N].
// One block = N threads (thread t owns output column t), R rows per block.
// A-rows staged in LDS (broadcast reads), B streamed from L2 (B is <=512KB,
// L2-resident). R=16 => B traffic = M/16 * K*N*4 bytes ~ 1.6GB L2 for layer 1.
// ---------------------------------------------------------------------------
template <int K, int N, int R>
__global__ __launch_bounds__(N) void gemm_rb(const float* __restrict__ A,
                                             const float* __restrict__ B,
                                             float* __restrict__ C) {
    __shared__ float xs[R][K];
    const int c = threadIdx.x;          // output column
    const int row0 = blockIdx.x * R;    // M divisible by R (50000 % 16 == 0)

    // cooperative float4 load of R rows of A into LDS
    const float4* A4 = (const float4*)(A + (size_t)row0 * K);
    float4* xs4 = (float4*)&xs[0][0];
    constexpr int TOT = R * K / 4;
    for (int i = c; i < TOT; i += N) xs4[i] = A4[i];
    __syncthreads();

    float acc[R];
#pragma unroll
    for (int r = 0; r < R; ++r) acc[r] = 0.f;

    for (int k = 0; k < K; k += 4) {
        const float w0 = B[(k + 0) * N + c];
        const float w1 = B[(k + 1) * N + c];
        const float w2 = B[(k + 2) * N + c];
        const float w3 = B[(k + 3) * N + c];
#pragma unroll
        for (int r = 0; r < R; ++r) {
            const float4 xv = *(const float4*)&xs[r][k];
            acc[r] = fmaf(xv.x, w0,
                     fmaf(xv.y, w1,
                     fmaf(xv.z, w2,
                     fmaf(xv.w, w3, acc[r]))));
        }
    }

#pragma unroll
    for (int r = 0; r < R; ++r) C[(size_t)(row0 + r) * N + c] = acc[r];
}

// ---------------------------------------------------------------------------
// Edge scatter: agg[dst] += S[src], one edge per D/4 lanes (float4 per lane).
// eg layout: eg[0..nE) = src, eg[nE..2nE) = dst.
// ---------------------------------------------------------------------------
template <int D>
__global__ void scatter_add(const float* __restrict__ S,
                            const int* __restrict__ eg,
                            float* __restrict__ agg) {
    constexpr int LPE = D / 4;  // lanes per edge
    const int gtid = blockIdx.x * blockDim.x + threadIdx.x;
    const int e = gtid / LPE;
    const int l = gtid % LPE;
    if (e >= N_EDGES) return;
    const int s = eg[e];
    const int d = eg[N_EDGES + e];
    const float4 v = *(const float4*)(S + (size_t)s * D + 4 * l);
    float* Ap = agg + (size_t)d * D + 4 * l;
    atomicAdd(Ap + 0, v.x);
    atomicAdd(Ap + 1, v.y);
    atomicAdd(Ap + 2, v.z);
    atomicAdd(Ap + 3, v.w);
}

// ---------------------------------------------------------------------------
// out = relu(X + b), in place. D power of two.
// ---------------------------------------------------------------------------
template <int D>
__global__ void bias_relu(float* __restrict__ X, const float* __restrict__ b,
                          int total) {
    for (int i = blockIdx.x * blockDim.x + threadIdx.x; i < total;
         i += gridDim.x * blockDim.x) {
        const float v = X[i] + b[i & (D - 1)];
        X[i] = v > 0.f ? v : 0.f;
    }
}

extern "C" void kernel_launch(void* const* d_in, const int* in_sizes, int n_in,
                              void* d_out, int out_size, void* d_ws, size_t ws_size,
                              hipStream_t stream) {
    const float* x  = (const float*)d_in[0];
    const int*   eg = (const int*)d_in[1];
    const float* W1 = (const float*)d_in[2];
    const float* b1 = (const float*)d_in[3];
    const float* W2 = (const float*)d_in[4];
    const float* b2 = (const float*)d_in[5];
    float* out = (float*)d_out;

    char* ws = (char*)d_ws;
    float* support1 = (float*)ws;                    // 50000*256*4 = 51.2 MB
    float* agg1     = (float*)(ws + 51200000);       // 51.2 MB (becomes x1)
    float* support2 = (float*)ws;                    // reuse slot 0: 25.6 MB

    // ---- layer 1 ----
    gemm_rb<512, 256, 16><<<N_NODES / 16, 256, 0, stream>>>(x, W1, support1);
    hipMemsetAsync(agg1, 0, (size_t)N_NODES * 256 * 4, stream);
    scatter_add<256><<<(N_EDGES * 64) / 256, 256, 0, stream>>>(support1, eg, agg1);
    bias_relu<256><<<2048, 256, 0, stream>>>(agg1, b1, N_NODES * 256);

    // ---- layer 2 ----
    gemm_rb<256, 128, 16><<<N_NODES / 16, 128, 0, stream>>>(agg1, W2, support2);
    hipMemsetAsync(out, 0, (size_t)N_NODES * 128 * 4, stream);
    scatter_add<128><<<(N_EDGES * 32) / 256, 256, 0, stream>>>(support2, eg, out);
    bias_relu<128><<<2048, 256, 0, stream>>>(out, b2, N_NODES * 128);
}

// Round 2
// 683.222 us; speedup vs baseline: 6.4189x; 6.4189x over previous
//
#include <hip/hip_runtime.h>

#define N_NODES 50000
#define N_EDGES 800000

// ---------------------------------------------------------------------------
// Register-blocked f32 GEMM: C[M,N] = A[M,K] @ B[K,N].
// One block = N threads (thread t owns output column t), R rows per block.
// ---------------------------------------------------------------------------
template <int K, int N, int R>
__global__ __launch_bounds__(N) void gemm_rb(const float* __restrict__ A,
                                             const float* __restrict__ B,
                                             float* __restrict__ C) {
    __shared__ float xs[R][K];
    const int c = threadIdx.x;
    const int row0 = blockIdx.x * R;

    const float4* A4 = (const float4*)(A + (size_t)row0 * K);
    float4* xs4 = (float4*)&xs[0][0];
    constexpr int TOT = R * K / 4;
    for (int i = c; i < TOT; i += N) xs4[i] = A4[i];
    __syncthreads();

    float acc[R];
#pragma unroll
    for (int r = 0; r < R; ++r) acc[r] = 0.f;

    for (int k = 0; k < K; k += 4) {
        const float w0 = B[(k + 0) * N + c];
        const float w1 = B[(k + 1) * N + c];
        const float w2 = B[(k + 2) * N + c];
        const float w3 = B[(k + 3) * N + c];
#pragma unroll
        for (int r = 0; r < R; ++r) {
            const float4 xv = *(const float4*)&xs[r][k];
            acc[r] = fmaf(xv.x, w0,
                     fmaf(xv.y, w1,
                     fmaf(xv.z, w2,
                     fmaf(xv.w, w3, acc[r]))));
        }
    }

#pragma unroll
    for (int r = 0; r < R; ++r) C[(size_t)(row0 + r) * N + c] = acc[r];
}

// ---------------------------------------------------------------------------
// CSR build: histogram by dst -> in-place exclusive scan -> bucket fill.
// ---------------------------------------------------------------------------
__global__ void edge_hist(const int* __restrict__ eg, int* __restrict__ cnt) {
    const int e = blockIdx.x * blockDim.x + threadIdx.x;
    if (e >= N_EDGES) return;
    atomicAdd(&cnt[eg[N_EDGES + e]], 1);
}

// Single-block in-place exclusive scan of a[0..N_NODES), writes total to
// a[N_NODES], and mirrors the exclusive prefix into cur[].
__global__ __launch_bounds__(1024) void scan_rowptr(int* __restrict__ a,
                                                    int* __restrict__ cur) {
    __shared__ int buf[1024];
    __shared__ int carry_s;
    const int t = threadIdx.x;
    if (t == 0) carry_s = 0;
    __syncthreads();
    for (int base = 0; base < N_NODES; base += 1024) {
        const int i = base + t;
        const int v = (i < N_NODES) ? a[i] : 0;
        buf[t] = v;
        __syncthreads();
        for (int off = 1; off < 1024; off <<= 1) {
            const int x = (t >= off) ? buf[t - off] : 0;
            __syncthreads();
            buf[t] += x;
            __syncthreads();
        }
        const int excl = carry_s + buf[t] - v;
        if (i < N_NODES) { a[i] = excl; cur[i] = excl; }
        __syncthreads();
        if (t == 0) carry_s += buf[1023];
        __syncthreads();
    }
    if (t == 0) a[N_NODES] = carry_s;
}

__global__ void csr_fill(const int* __restrict__ eg, int* __restrict__ cur,
                         int* __restrict__ csr_src) {
    const int e = blockIdx.x * blockDim.x + threadIdx.x;
    if (e >= N_EDGES) return;
    const int d = eg[N_EDGES + e];
    const int p = atomicAdd(&cur[d], 1);
    csr_src[p] = eg[e];
}

// ---------------------------------------------------------------------------
// Gather aggregation + fused bias + ReLU.
// D/4 lanes per node; each lane owns one float4 column slice.
// ---------------------------------------------------------------------------
template <int D>
__global__ void gather_bias_relu(const float* __restrict__ S,
                                 const int* __restrict__ rowptr,
                                 const int* __restrict__ csr_src,
                                 const float* __restrict__ bias,
                                 float* __restrict__ out) {
    constexpr int LPN = D / 4;
    const int gtid = blockIdx.x * blockDim.x + threadIdx.x;
    const int node = gtid / LPN;
    const int l = gtid % LPN;
    if (node >= N_NODES) return;
    const int beg = rowptr[node];
    const int end = rowptr[node + 1];
    float4 acc = make_float4(0.f, 0.f, 0.f, 0.f);
    for (int j = beg; j < end; ++j) {
        const int s = csr_src[j];
        const float4 v = *(const float4*)(S + (size_t)s * D + 4 * l);
        acc.x += v.x; acc.y += v.y; acc.z += v.z; acc.w += v.w;
    }
    const float4 b = *(const float4*)(bias + 4 * l);
    acc.x = fmaxf(acc.x + b.x, 0.f);
    acc.y = fmaxf(acc.y + b.y, 0.f);
    acc.z = fmaxf(acc.z + b.z, 0.f);
    acc.w = fmaxf(acc.w + b.w, 0.f);
    *(float4*)(out + (size_t)node * D + 4 * l) = acc;
}

// ---------------------------------------------------------------------------
// Fallback path kernels (atomic scatter), used only if ws_size is too small.
// ---------------------------------------------------------------------------
template <int D>
__global__ void scatter_add(const float* __restrict__ S,
                            const int* __restrict__ eg,
                            float* __restrict__ agg) {
    constexpr int LPE = D / 4;
    const int gtid = blockIdx.x * blockDim.x + threadIdx.x;
    const int e = gtid / LPE;
    const int l = gtid % LPE;
    if (e >= N_EDGES) return;
    const int s = eg[e];
    const int d = eg[N_EDGES + e];
    const float4 v = *(const float4*)(S + (size_t)s * D + 4 * l);
    float* Ap = agg + (size_t)d * D + 4 * l;
    atomicAdd(Ap + 0, v.x);
    atomicAdd(Ap + 1, v.y);
    atomicAdd(Ap + 2, v.z);
    atomicAdd(Ap + 3, v.w);
}

template <int D>
__global__ void bias_relu(float* __restrict__ X, const float* __restrict__ b,
                          int total) {
    for (int i = blockIdx.x * blockDim.x + threadIdx.x; i < total;
         i += gridDim.x * blockDim.x) {
        const float v = X[i] + b[i & (D - 1)];
        X[i] = v > 0.f ? v : 0.f;
    }
}

extern "C" void kernel_launch(void* const* d_in, const int* in_sizes, int n_in,
                              void* d_out, int out_size, void* d_ws, size_t ws_size,
                              hipStream_t stream) {
    const float* x  = (const float*)d_in[0];
    const int*   eg = (const int*)d_in[1];
    const float* W1 = (const float*)d_in[2];
    const float* b1 = (const float*)d_in[3];
    const float* W2 = (const float*)d_in[4];
    const float* b2 = (const float*)d_in[5];
    float* out = (float*)d_out;

    char* ws = (char*)d_ws;
    const size_t SUP1_OFF = 0;                        // 51.2 MB
    const size_t AGG1_OFF = 51200000;                 // 51.2 MB
    const size_t ROWPTR_OFF = 102400000;              // 50001 ints
    const size_t CUR_OFF = ROWPTR_OFF + 204800;       // 50000 ints
    const size_t CSRSRC_OFF = CUR_OFF + 204800;       // 800000 ints
    const size_t NEEDED = CSRSRC_OFF + (size_t)N_EDGES * 4;

    float* support1 = (float*)(ws + SUP1_OFF);
    float* agg1     = (float*)(ws + AGG1_OFF);
    float* support2 = (float*)(ws + SUP1_OFF);        // reuse slot 0

    if (ws_size >= NEEDED) {
        int* rowptr  = (int*)(ws + ROWPTR_OFF);
        int* cur     = (int*)(ws + CUR_OFF);
        int* csr_src = (int*)(ws + CSRSRC_OFF);

        // ---- CSR build (shared by both layers) ----
        hipMemsetAsync(rowptr, 0, (N_NODES + 1) * sizeof(int), stream);
        edge_hist<<<(N_EDGES + 255) / 256, 256, 0, stream>>>(eg, rowptr);
        scan_rowptr<<<1, 1024, 0, stream>>>(rowptr, cur);
        csr_fill<<<(N_EDGES + 255) / 256, 256, 0, stream>>>(eg, cur, csr_src);

        // ---- layer 1 ----
        gemm_rb<512, 256, 16><<<N_NODES / 16, 256, 0, stream>>>(x, W1, support1);
        gather_bias_relu<256><<<(N_NODES * 64) / 256, 256, 0, stream>>>(
            support1, rowptr, csr_src, b1, agg1);

        // ---- layer 2 ----
        gemm_rb<256, 128, 16><<<N_NODES / 16, 128, 0, stream>>>(agg1, W2, support2);
        gather_bias_relu<128><<<(N_NODES * 32) / 256, 256, 0, stream>>>(
            support2, rowptr, csr_src, b2, out);
    } else {
        // fallback: proven atomic-scatter path
        gemm_rb<512, 256, 16><<<N_NODES / 16, 256, 0, stream>>>(x, W1, support1);
        hipMemsetAsync(agg1, 0, (size_t)N_NODES * 256 * 4, stream);
        scatter_add<256><<<(N_EDGES * 64) / 256, 256, 0, stream>>>(support1, eg, agg1);
        bias_relu<256><<<2048, 256, 0, stream>>>(agg1, b1, N_NODES * 256);

        gemm_rb<256, 128, 16><<<N_NODES / 16, 128, 0, stream>>>(agg1, W2, support2);
        hipMemsetAsync(out, 0, (size_t)N_NODES * 128 * 4, stream);
        scatter_add<128><<<(N_EDGES * 32) / 256, 256, 0, stream>>>(support2, eg, out);
        bias_relu<128><<<2048, 256, 0, stream>>>(out, b2, N_NODES * 128);
    }
}

// Round 3
// 292.764 us; speedup vs baseline: 14.9798x; 2.3337x over previous
//
#include <hip/hip_runtime.h>

#define N_NODES 50000
#define N_EDGES 800000
#define MP 50176  // 392 * 128, padded M for GEMM tiles

typedef unsigned short ushort_t;
typedef unsigned int uint_t;
using short8 = __attribute__((ext_vector_type(8))) short;
using f32x4 = __attribute__((ext_vector_type(4))) float;

__device__ __forceinline__ ushort_t f2bf(float f) {
    uint_t u;
    __builtin_memcpy(&u, &f, 4);
    u = u + 0x7FFF + ((u >> 16) & 1);  // RNE
    return (ushort_t)(u >> 16);
}

__device__ __forceinline__ float bf2f(ushort_t h) {
    uint_t u = ((uint_t)h) << 16;
    float f;
    __builtin_memcpy(&f, &u, 4);
    return f;
}

__device__ __forceinline__ void async_copy16(const void* g, const void* l) {
    __builtin_amdgcn_global_load_lds(
        (const __attribute__((address_space(1))) uint_t*)g,
        (__attribute__((address_space(3))) uint_t*)l, 16, 0, 0);
}

// ---------------------------------------------------------------------------
// f32 -> bf16 flat convert (4 elems/thread).
// ---------------------------------------------------------------------------
__global__ void f32_to_bf16(const float* __restrict__ in,
                            ushort_t* __restrict__ out, int total4) {
    const int i = blockIdx.x * blockDim.x + threadIdx.x;
    if (i >= total4) return;
    const float4 v = *(const float4*)(in + (size_t)i * 4);
    ushort4 o;
    o.x = f2bf(v.x); o.y = f2bf(v.y); o.z = f2bf(v.z); o.w = f2bf(v.w);
    *(ushort4*)(out + (size_t)i * 4) = o;
}

// W [K,N] f32 -> Wt [N,K] bf16
__global__ void transpose_f32_bf16(const float* __restrict__ W,
                                   ushort_t* __restrict__ Wt, int K, int N) {
    const int i = blockIdx.x * blockDim.x + threadIdx.x;
    if (i >= K * N) return;
    const int n = i / K, k = i - n * K;
    Wt[i] = f2bf(W[(size_t)k * N + n]);
}

// ---------------------------------------------------------------------------
// CSR build
// ---------------------------------------------------------------------------
__global__ void edge_hist(const int* __restrict__ eg, int* __restrict__ cnt) {
    const int e = blockIdx.x * blockDim.x + threadIdx.x;
    if (e >= N_EDGES) return;
    atomicAdd(&cnt[eg[N_EDGES + e]], 1);
}

__global__ __launch_bounds__(1024) void scan_rowptr(int* __restrict__ a,
                                                    int* __restrict__ cur) {
    __shared__ int wsum[16];
    __shared__ int carry_s, ctot;
    const int t = threadIdx.x, wid = t >> 6, lane = t & 63;
    if (t == 0) carry_s = 0;
    for (int base = 0; base < N_NODES; base += 1024) {
        const int i = base + t;
        const int v = (i < N_NODES) ? a[i] : 0;
        int s = v;
#pragma unroll
        for (int off = 1; off < 64; off <<= 1) {
            const int u = __shfl_up(s, off, 64);
            if (lane >= off) s += u;
        }
        if (lane == 63) wsum[wid] = s;
        __syncthreads();
        if (wid == 0) {
            const int wv = (lane < 16) ? wsum[lane] : 0;
            int ss = wv;
#pragma unroll
            for (int off = 1; off < 16; off <<= 1) {
                const int u = __shfl_up(ss, off, 64);
                if (lane >= off) ss += u;
            }
            if (lane < 16) wsum[lane] = ss - wv;  // exclusive wave offsets
            if (lane == 15) ctot = ss;            // chunk total
        }
        __syncthreads();
        if (i < N_NODES) {
            const int excl = carry_s + wsum[wid] + (s - v);
            a[i] = excl;
            cur[i] = excl;
        }
        __syncthreads();
        if (t == 0) carry_s += ctot;
        __syncthreads();
    }
    if (threadIdx.x == 0) a[N_NODES] = carry_s;
}

__global__ void csr_fill(const int* __restrict__ eg, int* __restrict__ cur,
                         int* __restrict__ csr_src) {
    const int e = blockIdx.x * blockDim.x + threadIdx.x;
    if (e >= N_EDGES) return;
    const int d = eg[N_EDGES + e];
    const int p = atomicAdd(&cur[d], 1);
    csr_src[p] = eg[e];
}

// ---------------------------------------------------------------------------
// bf16 MFMA GEMM: C[MP,N] = A[MP,K] @ Bt[N,K]^T, all row-major bf16.
// BM=128, BN=128, BK=64, 4 waves (2x2), acc 4x4 frags of 16x16x32.
// LDS tiles XOR-swizzled (T2): 16B slot ^= (row&7); staged via
// global_load_lds with pre-swizzled global source (rule #21).
// ---------------------------------------------------------------------------
template <int K>
__global__ __launch_bounds__(256) void gemm_mfma(const ushort_t* __restrict__ A,
                                                 const ushort_t* __restrict__ Bt,
                                                 ushort_t* __restrict__ C,
                                                 int N) {
    __shared__ ushort_t lA[128 * 64];
    __shared__ ushort_t lB[128 * 64];
    const int tid = threadIdx.x;
    const int w = tid >> 6;
    const int lane = tid & 63;
    const int wr = w >> 1, wc = w & 1;
    const int m0 = blockIdx.x * 128;
    const int n0 = blockIdx.y * 128;

    const int sr = lane >> 3;  // row within 8-row staging group
    const int sj = lane & 7;   // 16B slot within 128B row

    f32x4 acc[4][4];
#pragma unroll
    for (int m = 0; m < 4; ++m)
#pragma unroll
        for (int n = 0; n < 4; ++n) acc[m][n] = (f32x4){0.f, 0.f, 0.f, 0.f};

    const char* Ab = (const char*)A;
    const char* Bb = (const char*)Bt;

    for (int kt = 0; kt < K / 64; ++kt) {
#pragma unroll
        for (int i = 0; i < 4; ++i) {  // stage A: wave covers rows [w*32, w*32+32)
            const int r = w * 32 + i * 8 + sr;
            const char* g = Ab + ((size_t)(m0 + r) * K + kt * 64) * 2 +
                            ((size_t)(sj ^ (r & 7)) << 4);
            async_copy16(g, lA + (size_t)(w * 32 + i * 8) * 64);
        }
#pragma unroll
        for (int i = 0; i < 4; ++i) {  // stage B (Bt rows = output cols)
            const int r = w * 32 + i * 8 + sr;
            const char* g = Bb + ((size_t)(n0 + r) * K + kt * 64) * 2 +
                            ((size_t)(sj ^ (r & 7)) << 4);
            async_copy16(g, lB + (size_t)(w * 32 + i * 8) * 64);
        }
        __syncthreads();

        const int g = lane >> 4;    // k-group 0..3
        const int rr = lane & 15;   // row/col within frag
#pragma unroll
        for (int kk = 0; kk < 2; ++kk) {
            short8 av[4], bv[4];
#pragma unroll
            for (int m = 0; m < 4; ++m) {
                const int row = wr * 64 + m * 16 + rr;
                const int slot = (kk * 4 + g) ^ (row & 7);
                av[m] = *(const short8*)((const char*)lA + row * 128 + slot * 16);
            }
#pragma unroll
            for (int n = 0; n < 4; ++n) {
                const int row = wc * 64 + n * 16 + rr;
                const int slot = (kk * 4 + g) ^ (row & 7);
                bv[n] = *(const short8*)((const char*)lB + row * 128 + slot * 16);
            }
#pragma unroll
            for (int m = 0; m < 4; ++m)
#pragma unroll
                for (int n = 0; n < 4; ++n)
                    acc[m][n] = __builtin_amdgcn_mfma_f32_16x16x32_bf16(
                        av[m], bv[n], acc[m][n], 0, 0, 0);
        }
        __syncthreads();
    }

    // epilogue: C/D layout col=lane&15, row=(lane>>4)*4+q (measured, m89/m91)
    const int rr = lane & 15;
    const int rg = lane >> 4;
#pragma unroll
    for (int m = 0; m < 4; ++m)
#pragma unroll
        for (int n = 0; n < 4; ++n)
#pragma unroll
            for (int q = 0; q < 4; ++q) {
                const int row = m0 + wr * 64 + m * 16 + rg * 4 + q;
                const int col = n0 + wc * 64 + n * 16 + rr;
                C[(size_t)row * N + col] = f2bf(acc[m][n][q]);
            }
}

// ---------------------------------------------------------------------------
// Gather aggregation over bf16 support + fused bias + ReLU.
// D/8 lanes per node, 8 bf16 (16B) per lane. OUT_BF16 -> bf16 out, else f32.
// ---------------------------------------------------------------------------
template <int D, bool OUT_BF16>
__global__ void gather_bias_relu(const ushort_t* __restrict__ S,
                                 const int* __restrict__ rowptr,
                                 const int* __restrict__ csr_src,
                                 const float* __restrict__ bias,
                                 void* __restrict__ out) {
    constexpr int LPN = D / 8;
    const int gtid = blockIdx.x * blockDim.x + threadIdx.x;
    const int node = gtid / LPN;
    const int l = gtid % LPN;
    if (node >= N_NODES) return;
    const int beg = rowptr[node];
    const int end = rowptr[node + 1];

    float acc0[8], acc1[8];
#pragma unroll
    for (int k = 0; k < 8; ++k) { acc0[k] = 0.f; acc1[k] = 0.f; }

    int j = beg;
    for (; j + 2 <= end; j += 2) {
        const int s0 = csr_src[j];
        const int s1 = csr_src[j + 1];
        const short8 v0 = *(const short8*)(S + (size_t)s0 * D + 8 * l);
        const short8 v1 = *(const short8*)(S + (size_t)s1 * D + 8 * l);
#pragma unroll
        for (int k = 0; k < 8; ++k) {
            acc0[k] += bf2f((ushort_t)v0[k]);
            acc1[k] += bf2f((ushort_t)v1[k]);
        }
    }
    if (j < end) {
        const int s0 = csr_src[j];
        const short8 v0 = *(const short8*)(S + (size_t)s0 * D + 8 * l);
#pragma unroll
        for (int k = 0; k < 8; ++k) acc0[k] += bf2f((ushort_t)v0[k]);
    }

#pragma unroll
    for (int k = 0; k < 8; ++k) {
        acc0[k] = fmaxf(acc0[k] + acc1[k] + bias[8 * l + k], 0.f);
    }

    if (OUT_BF16) {
        short8 o;
#pragma unroll
        for (int k = 0; k < 8; ++k) o[k] = (short)f2bf(acc0[k]);
        *(short8*)((ushort_t*)out + (size_t)node * D + 8 * l) = o;
    } else {
        float* op = (float*)out + (size_t)node * D + 8 * l;
        *(float4*)(op + 0) = make_float4(acc0[0], acc0[1], acc0[2], acc0[3]);
        *(float4*)(op + 4) = make_float4(acc0[4], acc0[5], acc0[6], acc0[7]);
    }
}

// ---------------------------------------------------------------------------
extern "C" void kernel_launch(void* const* d_in, const int* in_sizes, int n_in,
                              void* d_out, int out_size, void* d_ws, size_t ws_size,
                              hipStream_t stream) {
    const float* x  = (const float*)d_in[0];
    const int*   eg = (const int*)d_in[1];
    const float* W1 = (const float*)d_in[2];
    const float* b1 = (const float*)d_in[3];
    const float* W2 = (const float*)d_in[4];
    const float* b2 = (const float*)d_in[5];
    float* out = (float*)d_out;

    char* ws = (char*)d_ws;
    // layout (bytes); xb is dead after gemm1 so agg1/sup2 overlay it
    const size_t SUP1_OFF = 0;              // MP*256*2 = 25,690,112
    const size_t XB_OFF   = 25690112;       // MP*512*2 = 51,380,224 (dies after gemm1)
    const size_t AGG1_OFF = 25690112;       // MP*256*2 (overlays xb lower half)
    const size_t SUP2_OFF = 51380224;       // MP*128*2 = 12,845,056 (inside old xb)
    const size_t W1T_OFF  = 77070336;       // 256*512*2 = 262,144
    const size_t W2T_OFF  = 77332480;       // 128*256*2 = 65,536
    const size_t RP_OFF   = 77398016;       // (50001)*4 -> pad 200,016
    const size_t CUR_OFF  = 77598032;       // 200,000
    const size_t CSR_OFF  = 77798032;       // 3,200,000  (end ~81.0 MB)

    ushort_t* sup1 = (ushort_t*)(ws + SUP1_OFF);
    ushort_t* xb   = (ushort_t*)(ws + XB_OFF);
    ushort_t* agg1 = (ushort_t*)(ws + AGG1_OFF);
    ushort_t* sup2 = (ushort_t*)(ws + SUP2_OFF);
    ushort_t* W1t  = (ushort_t*)(ws + W1T_OFF);
    ushort_t* W2t  = (ushort_t*)(ws + W2T_OFF);
    int* rowptr  = (int*)(ws + RP_OFF);
    int* cur     = (int*)(ws + CUR_OFF);
    int* csr_src = (int*)(ws + CSR_OFF);

    // ---- input conversion ----
    f32_to_bf16<<<(N_NODES * 512 / 4 + 255) / 256, 256, 0, stream>>>(
        x, xb, N_NODES * 512 / 4);
    transpose_f32_bf16<<<(512 * 256 + 255) / 256, 256, 0, stream>>>(W1, W1t, 512, 256);
    transpose_f32_bf16<<<(256 * 128 + 255) / 256, 256, 0, stream>>>(W2, W2t, 256, 128);

    // ---- CSR build ----
    hipMemsetAsync(rowptr, 0, (N_NODES + 1) * sizeof(int), stream);
    edge_hist<<<(N_EDGES + 255) / 256, 256, 0, stream>>>(eg, rowptr);
    scan_rowptr<<<1, 1024, 0, stream>>>(rowptr, cur);
    csr_fill<<<(N_EDGES + 255) / 256, 256, 0, stream>>>(eg, cur, csr_src);

    // ---- layer 1 ----
    gemm_mfma<512><<<dim3(MP / 128, 2), 256, 0, stream>>>(xb, W1t, sup1, 256);
    gather_bias_relu<256, true><<<(N_NODES * 32 + 255) / 256, 256, 0, stream>>>(
        sup1, rowptr, csr_src, b1, agg1);

    // ---- layer 2 ----
    gemm_mfma<256><<<dim3(MP / 128, 1), 256, 0, stream>>>(agg1, W2t, sup2, 128);
    gather_bias_relu<128, false><<<(N_NODES * 16 + 255) / 256, 256, 0, stream>>>(
        sup2, rowptr, csr_src, b2, out);
}

// Round 4
// 247.340 us; speedup vs baseline: 17.7309x; 1.1837x over previous
//
#include <hip/hip_runtime.h>

#define N_NODES 50000
#define N_EDGES 800000
#define MP 50176  // 392 * 128, padded M for GEMM tiles

typedef unsigned short ushort_t;
typedef unsigned int uint_t;
using short8 = __attribute__((ext_vector_type(8))) short;
using f32x4 = __attribute__((ext_vector_type(4))) float;

__device__ __forceinline__ ushort_t f2bf(float f) {
    uint_t u;
    __builtin_memcpy(&u, &f, 4);
    u = u + 0x7FFF + ((u >> 16) & 1);  // RNE
    return (ushort_t)(u >> 16);
}

__device__ __forceinline__ float bf2f(ushort_t h) {
    uint_t u = ((uint_t)h) << 16;
    float f;
    __builtin_memcpy(&f, &u, 4);
    return f;
}

__device__ __forceinline__ void async_copy16(const void* g, const void* l) {
    __builtin_amdgcn_global_load_lds(
        (const __attribute__((address_space(1))) uint_t*)g,
        (__attribute__((address_space(3))) uint_t*)l, 16, 0, 0);
}

// ---------------------------------------------------------------------------
// prep: zero rowptr (replaces 58us fillBuffer!) + transpose both W to bf16.
// grid: 512 blocks x 256 threads.
// ---------------------------------------------------------------------------
__global__ __launch_bounds__(256) void prep(const float* __restrict__ W1,
                                            const float* __restrict__ W2,
                                            ushort_t* __restrict__ W1t,
                                            ushort_t* __restrict__ W2t,
                                            int* __restrict__ rowptr) {
    const int i = blockIdx.x * blockDim.x + threadIdx.x;
    if (i < 256 * 512) {               // W1t[n][k] = W1[k][n]
        const int n = i >> 9, k = i & 511;
        W1t[i] = f2bf(W1[(size_t)k * 256 + n]);
    }
    if (i < 128 * 256) {               // W2t[n][k] = W2[k][n]
        const int n = i >> 8, k = i & 255;
        W2t[i] = f2bf(W2[(size_t)k * 128 + n]);
    }
    if (i <= N_NODES) rowptr[i] = 0;
}

// ---------------------------------------------------------------------------
// f32 -> bf16 flat convert (4 elems/thread).
// ---------------------------------------------------------------------------
__global__ void f32_to_bf16(const float* __restrict__ in,
                            ushort_t* __restrict__ out, int total4) {
    const int i = blockIdx.x * blockDim.x + threadIdx.x;
    if (i >= total4) return;
    const float4 v = *(const float4*)(in + (size_t)i * 4);
    ushort4 o;
    o.x = f2bf(v.x); o.y = f2bf(v.y); o.z = f2bf(v.z); o.w = f2bf(v.w);
    *(ushort4*)(out + (size_t)i * 4) = o;
}

// ---------------------------------------------------------------------------
// CSR build: hist -> per-block scan -> add block offsets -> fill.
// ---------------------------------------------------------------------------
__global__ void edge_hist(const int* __restrict__ eg, int* __restrict__ cnt) {
    const int e = blockIdx.x * blockDim.x + threadIdx.x;
    if (e >= N_EDGES) return;
    atomicAdd(&cnt[eg[N_EDGES + e]], 1);
}

// per-block exclusive scan of a[0..N_NODES); block totals to bsum.
__global__ __launch_bounds__(256) void scan_blocks(int* __restrict__ a,
                                                   int* __restrict__ bsum) {
    __shared__ int wsum[4];
    const int t = threadIdx.x, lane = t & 63, wid = t >> 6;
    const int i = blockIdx.x * 256 + t;
    const int v = (i < N_NODES) ? a[i] : 0;
    int s = v;
#pragma unroll
    for (int off = 1; off < 64; off <<= 1) {
        const int u = __shfl_up(s, off, 64);
        if (lane >= off) s += u;
    }
    if (lane == 63) wsum[wid] = s;
    __syncthreads();
    if (t == 0) {
        const int a0 = wsum[0], a1 = wsum[1], a2 = wsum[2], a3 = wsum[3];
        wsum[0] = 0; wsum[1] = a0; wsum[2] = a0 + a1; wsum[3] = a0 + a1 + a2;
        bsum[blockIdx.x] = a0 + a1 + a2 + a3;
    }
    __syncthreads();
    if (i < N_NODES) a[i] = wsum[wid] + s - v;
}

// add cross-block offsets; mirror into cur; write total to a[N_NODES].
__global__ __launch_bounds__(256) void add_offsets(int* __restrict__ a,
                                                   int* __restrict__ cur,
                                                   const int* __restrict__ bsum) {
    __shared__ int off_s;
    const int t = threadIdx.x, b = blockIdx.x;
    if (t == 0) off_s = 0;
    __syncthreads();
    int partial = 0;
    for (int j = t; j < b; j += 256) partial += bsum[j];
#pragma unroll
    for (int off = 32; off >= 1; off >>= 1) partial += __shfl_down(partial, off, 64);
    if ((t & 63) == 0) atomicAdd(&off_s, partial);
    __syncthreads();
    const int off = off_s;
    const int i = b * 256 + t;
    if (i < N_NODES) { const int v = a[i] + off; a[i] = v; cur[i] = v; }
    if (b == gridDim.x - 1 && t == 0) a[N_NODES] = off + bsum[b];
}

__global__ void csr_fill(const int* __restrict__ eg, int* __restrict__ cur,
                         int* __restrict__ csr_src) {
    const int e = blockIdx.x * blockDim.x + threadIdx.x;
    if (e >= N_EDGES) return;
    const int d = eg[N_EDGES + e];
    const int p = atomicAdd(&cur[d], 1);
    csr_src[p] = eg[e];
}

// ---------------------------------------------------------------------------
// bf16 MFMA GEMM: C[MP,N] = A[MP,K] @ Bt[N,K]^T, all row-major bf16.
// BM=128, BN=128, BK=64, 4 waves (2x2), acc 4x4 frags of 16x16x32.
// LDS tiles XOR-swizzled (T2) via pre-swizzled global source (rule #21).
// ---------------------------------------------------------------------------
template <int K>
__global__ __launch_bounds__(256) void gemm_mfma(const ushort_t* __restrict__ A,
                                                 const ushort_t* __restrict__ Bt,
                                                 ushort_t* __restrict__ C,
                                                 int N) {
    __shared__ ushort_t lA[128 * 64];
    __shared__ ushort_t lB[128 * 64];
    const int tid = threadIdx.x;
    const int w = tid >> 6;
    const int lane = tid & 63;
    const int wr = w >> 1, wc = w & 1;
    const int m0 = blockIdx.x * 128;
    const int n0 = blockIdx.y * 128;

    const int sr = lane >> 3;
    const int sj = lane & 7;

    f32x4 acc[4][4];
#pragma unroll
    for (int m = 0; m < 4; ++m)
#pragma unroll
        for (int n = 0; n < 4; ++n) acc[m][n] = (f32x4){0.f, 0.f, 0.f, 0.f};

    const char* Ab = (const char*)A;
    const char* Bb = (const char*)Bt;

    for (int kt = 0; kt < K / 64; ++kt) {
#pragma unroll
        for (int i = 0; i < 4; ++i) {
            const int r = w * 32 + i * 8 + sr;
            const char* g = Ab + ((size_t)(m0 + r) * K + kt * 64) * 2 +
                            ((size_t)(sj ^ (r & 7)) << 4);
            async_copy16(g, lA + (size_t)(w * 32 + i * 8) * 64);
        }
#pragma unroll
        for (int i = 0; i < 4; ++i) {
            const int r = w * 32 + i * 8 + sr;
            const char* g = Bb + ((size_t)(n0 + r) * K + kt * 64) * 2 +
                            ((size_t)(sj ^ (r & 7)) << 4);
            async_copy16(g, lB + (size_t)(w * 32 + i * 8) * 64);
        }
        __syncthreads();

        const int g = lane >> 4;
        const int rr = lane & 15;
#pragma unroll
        for (int kk = 0; kk < 2; ++kk) {
            short8 av[4], bv[4];
#pragma unroll
            for (int m = 0; m < 4; ++m) {
                const int row = wr * 64 + m * 16 + rr;
                const int slot = (kk * 4 + g) ^ (row & 7);
                av[m] = *(const short8*)((const char*)lA + row * 128 + slot * 16);
            }
#pragma unroll
            for (int n = 0; n < 4; ++n) {
                const int row = wc * 64 + n * 16 + rr;
                const int slot = (kk * 4 + g) ^ (row & 7);
                bv[n] = *(const short8*)((const char*)lB + row * 128 + slot * 16);
            }
#pragma unroll
            for (int m = 0; m < 4; ++m)
#pragma unroll
                for (int n = 0; n < 4; ++n)
                    acc[m][n] = __builtin_amdgcn_mfma_f32_16x16x32_bf16(
                        av[m], bv[n], acc[m][n], 0, 0, 0);
        }
        __syncthreads();
    }

    const int rr = lane & 15;
    const int rg = lane >> 4;
#pragma unroll
    for (int m = 0; m < 4; ++m)
#pragma unroll
        for (int n = 0; n < 4; ++n)
#pragma unroll
            for (int q = 0; q < 4; ++q) {
                const int row = m0 + wr * 64 + m * 16 + rg * 4 + q;
                const int col = n0 + wc * 64 + n * 16 + rr;
                C[(size_t)row * N + col] = f2bf(acc[m][n][q]);
            }
}

// ---------------------------------------------------------------------------
// Gather aggregation + fused bias + ReLU, 8-edge-deep MLP.
// D/8 lanes per node, 16B per lane per edge.
// ---------------------------------------------------------------------------
template <int D, bool OUT_BF16>
__global__ __launch_bounds__(256) void gather_bias_relu(
    const ushort_t* __restrict__ S, const int* __restrict__ rowptr,
    const int* __restrict__ csr_src, const float* __restrict__ bias,
    void* __restrict__ out) {
    constexpr int LPN = D / 8;
    const int gtid = blockIdx.x * blockDim.x + threadIdx.x;
    const int node = gtid / LPN;
    const int l = gtid % LPN;
    if (node >= N_NODES) return;
    const int beg = rowptr[node];
    const int end = rowptr[node + 1];
    const size_t coff = 8 * (size_t)l;

    float acc[8];
#pragma unroll
    for (int k = 0; k < 8; ++k) acc[k] = 0.f;

    int j = beg;
    for (; j + 8 <= end; j += 8) {
        int sidx[8];
#pragma unroll
        for (int q = 0; q < 8; ++q) sidx[q] = csr_src[j + q];
        short8 v[8];
#pragma unroll
        for (int q = 0; q < 8; ++q)
            v[q] = *(const short8*)(S + (size_t)sidx[q] * D + coff);
#pragma unroll
        for (int q = 0; q < 8; ++q)
#pragma unroll
            for (int k = 0; k < 8; ++k) acc[k] += bf2f((ushort_t)v[q][k]);
    }
    for (; j + 2 <= end; j += 2) {
        const int s0 = csr_src[j], s1 = csr_src[j + 1];
        const short8 v0 = *(const short8*)(S + (size_t)s0 * D + coff);
        const short8 v1 = *(const short8*)(S + (size_t)s1 * D + coff);
#pragma unroll
        for (int k = 0; k < 8; ++k)
            acc[k] += bf2f((ushort_t)v0[k]) + bf2f((ushort_t)v1[k]);
    }
    if (j < end) {
        const int s0 = csr_src[j];
        const short8 v0 = *(const short8*)(S + (size_t)s0 * D + coff);
#pragma unroll
        for (int k = 0; k < 8; ++k) acc[k] += bf2f((ushort_t)v0[k]);
    }

#pragma unroll
    for (int k = 0; k < 8; ++k) acc[k] = fmaxf(acc[k] + bias[coff + k], 0.f);

    if (OUT_BF16) {
        short8 o;
#pragma unroll
        for (int k = 0; k < 8; ++k) o[k] = (short)f2bf(acc[k]);
        *(short8*)((ushort_t*)out + (size_t)node * D + coff) = o;
    } else {
        float* op = (float*)out + (size_t)node * D + coff;
        *(float4*)(op + 0) = make_float4(acc[0], acc[1], acc[2], acc[3]);
        *(float4*)(op + 4) = make_float4(acc[4], acc[5], acc[6], acc[7]);
    }
}

// ---------------------------------------------------------------------------
extern "C" void kernel_launch(void* const* d_in, const int* in_sizes, int n_in,
                              void* d_out, int out_size, void* d_ws, size_t ws_size,
                              hipStream_t stream) {
    const float* x  = (const float*)d_in[0];
    const int*   eg = (const int*)d_in[1];
    const float* W1 = (const float*)d_in[2];
    const float* b1 = (const float*)d_in[3];
    const float* W2 = (const float*)d_in[4];
    const float* b2 = (const float*)d_in[5];
    float* out = (float*)d_out;

    char* ws = (char*)d_ws;
    const size_t SUP1_OFF = 0;              // MP*256*2 = 25,690,112
    const size_t XB_OFF   = 25690112;       // MP*512*2 (dies after gemm1)
    const size_t AGG1_OFF = 25690112;       // MP*256*2 (overlays xb)
    const size_t SUP2_OFF = 51380224;       // MP*128*2
    const size_t W1T_OFF  = 77070336;       // 262,144
    const size_t W2T_OFF  = 77332480;       // 65,536
    const size_t RP_OFF   = 77398016;       // 50001*4 (pad to 200,016)
    const size_t CUR_OFF  = 77598032;       // 200,000
    const size_t CSR_OFF  = 77798032;       // 3,200,000
    const size_t BSUM_OFF = 80998032;       // 196*4  (end ~81.0 MB)

    ushort_t* sup1 = (ushort_t*)(ws + SUP1_OFF);
    ushort_t* xb   = (ushort_t*)(ws + XB_OFF);
    ushort_t* agg1 = (ushort_t*)(ws + AGG1_OFF);
    ushort_t* sup2 = (ushort_t*)(ws + SUP2_OFF);
    ushort_t* W1t  = (ushort_t*)(ws + W1T_OFF);
    ushort_t* W2t  = (ushort_t*)(ws + W2T_OFF);
    int* rowptr  = (int*)(ws + RP_OFF);
    int* cur     = (int*)(ws + CUR_OFF);
    int* csr_src = (int*)(ws + CSR_OFF);
    int* bsum    = (int*)(ws + BSUM_OFF);

    const int SCAN_BLKS = (N_NODES + 255) / 256;  // 196

    // ---- prep: zero rowptr + W transposes ----
    prep<<<512, 256, 0, stream>>>(W1, W2, W1t, W2t, rowptr);

    // ---- input conversion ----
    f32_to_bf16<<<(N_NODES * 512 / 4 + 255) / 256, 256, 0, stream>>>(
        x, xb, N_NODES * 512 / 4);

    // ---- CSR build ----
    edge_hist<<<(N_EDGES + 255) / 256, 256, 0, stream>>>(eg, rowptr);
    scan_blocks<<<SCAN_BLKS, 256, 0, stream>>>(rowptr, bsum);
    add_offsets<<<SCAN_BLKS, 256, 0, stream>>>(rowptr, cur, bsum);
    csr_fill<<<(N_EDGES + 255) / 256, 256, 0, stream>>>(eg, cur, csr_src);

    // ---- layer 1 ----
    gemm_mfma<512><<<dim3(MP / 128, 2), 256, 0, stream>>>(xb, W1t, sup1, 256);
    gather_bias_relu<256, true><<<(N_NODES * 32 + 255) / 256, 256, 0, stream>>>(
        sup1, rowptr, csr_src, b1, agg1);

    // ---- layer 2 ----
    gemm_mfma<256><<<dim3(MP / 128, 1), 256, 0, stream>>>(agg1, W2t, sup2, 128);
    gather_bias_relu<128, false><<<(N_NODES * 16 + 255) / 256, 256, 0, stream>>>(
        sup2, rowptr, csr_src, b2, out);
}

// Round 5
// 247.309 us; speedup vs baseline: 17.7331x; 1.0001x over previous
//
#include <hip/hip_runtime.h>

#define N_NODES 50000
#define N_EDGES 800000
#define MP 50176  // 392 * 128, padded M for GEMM tiles

typedef unsigned short ushort_t;
typedef unsigned int uint_t;
using short8 = __attribute__((ext_vector_type(8))) short;
using f32x4 = __attribute__((ext_vector_type(4))) float;

__device__ __forceinline__ ushort_t f2bf(float f) {
    uint_t u;
    __builtin_memcpy(&u, &f, 4);
    u = u + 0x7FFF + ((u >> 16) & 1);  // RNE
    return (ushort_t)(u >> 16);
}

__device__ __forceinline__ float bf2f(ushort_t h) {
    uint_t u = ((uint_t)h) << 16;
    float f;
    __builtin_memcpy(&f, &u, 4);
    return f;
}

__device__ __forceinline__ void async_copy16(const void* g, const void* l) {
    __builtin_amdgcn_global_load_lds(
        (const __attribute__((address_space(1))) uint_t*)g,
        (__attribute__((address_space(3))) uint_t*)l, 16, 0, 0);
}

// ---------------------------------------------------------------------------
// prep: zero rowptr + pad csr_src + transpose both W to bf16.
// ---------------------------------------------------------------------------
__global__ __launch_bounds__(256) void prep(const float* __restrict__ W1,
                                            const float* __restrict__ W2,
                                            ushort_t* __restrict__ W1t,
                                            ushort_t* __restrict__ W2t,
                                            int* __restrict__ rowptr,
                                            int* __restrict__ csr_src) {
    const int i = blockIdx.x * blockDim.x + threadIdx.x;
    if (i < 256 * 512) {               // W1t[n][k] = W1[k][n]
        const int n = i >> 9, k = i & 511;
        W1t[i] = f2bf(W1[(size_t)k * 256 + n]);
    }
    if (i < 128 * 256) {               // W2t[n][k] = W2[k][n]
        const int n = i >> 8, k = i & 255;
        W2t[i] = f2bf(W2[(size_t)k * 128 + n]);
    }
    if (i <= N_NODES) rowptr[i] = 0;
    if (i < 16) csr_src[N_EDGES + i] = 0;  // safe pad for masked gather chunks
}

// ---------------------------------------------------------------------------
// CSR build: hist -> per-block scan -> add block offsets -> fill.
// ---------------------------------------------------------------------------
__global__ void edge_hist(const int* __restrict__ eg, int* __restrict__ cnt) {
    const int e = blockIdx.x * blockDim.x + threadIdx.x;
    if (e >= N_EDGES) return;
    atomicAdd(&cnt[eg[N_EDGES + e]], 1);
}

__global__ __launch_bounds__(256) void scan_blocks(int* __restrict__ a,
                                                   int* __restrict__ bsum) {
    __shared__ int wsum[4];
    const int t = threadIdx.x, lane = t & 63, wid = t >> 6;
    const int i = blockIdx.x * 256 + t;
    const int v = (i < N_NODES) ? a[i] : 0;
    int s = v;
#pragma unroll
    for (int off = 1; off < 64; off <<= 1) {
        const int u = __shfl_up(s, off, 64);
        if (lane >= off) s += u;
    }
    if (lane == 63) wsum[wid] = s;
    __syncthreads();
    if (t == 0) {
        const int a0 = wsum[0], a1 = wsum[1], a2 = wsum[2], a3 = wsum[3];
        wsum[0] = 0; wsum[1] = a0; wsum[2] = a0 + a1; wsum[3] = a0 + a1 + a2;
        bsum[blockIdx.x] = a0 + a1 + a2 + a3;
    }
    __syncthreads();
    if (i < N_NODES) a[i] = wsum[wid] + s - v;
}

__global__ __launch_bounds__(256) void add_offsets(int* __restrict__ a,
                                                   int* __restrict__ cur,
                                                   const int* __restrict__ bsum) {
    __shared__ int off_s;
    const int t = threadIdx.x, b = blockIdx.x;
    if (t == 0) off_s = 0;
    __syncthreads();
    int partial = 0;
    for (int j = t; j < b; j += 256) partial += bsum[j];
#pragma unroll
    for (int off = 32; off >= 1; off >>= 1) partial += __shfl_down(partial, off, 64);
    if ((t & 63) == 0) atomicAdd(&off_s, partial);
    __syncthreads();
    const int off = off_s;
    const int i = b * 256 + t;
    if (i < N_NODES) { const int v = a[i] + off; a[i] = v; cur[i] = v; }
    if (b == gridDim.x - 1 && t == 0) a[N_NODES] = off + bsum[b];
}

__global__ void csr_fill(const int* __restrict__ eg, int* __restrict__ cur,
                         int* __restrict__ csr_src) {
    const int e = blockIdx.x * blockDim.x + threadIdx.x;
    if (e >= N_EDGES) return;
    const int d = eg[N_EDGES + e];
    const int p = atomicAdd(&cur[d], 1);
    csr_src[p] = eg[e];
}

// ---------------------------------------------------------------------------
// bf16 MFMA GEMM: C[MP,N] = A[MP,K] @ Bt[N,K]^T, row-major.
// BM=128, BN=128, BK=64, 4 waves (2x2), acc 4x4 frags of 16x16x32.
// AF32: A is f32 and converted to bf16 during reg-staging (fused convert);
// else A is bf16 staged via global_load_lds with pre-swizzled source.
// LDS tiles XOR-swizzled: 16B slot ^= (row&7) on both write and read sides.
// ---------------------------------------------------------------------------
template <int K, bool AF32>
__global__ __launch_bounds__(256) void gemm_mfma(const void* __restrict__ Av,
                                                 const ushort_t* __restrict__ Bt,
                                                 ushort_t* __restrict__ C,
                                                 int N) {
    __shared__ ushort_t lA[128 * 64];
    __shared__ ushort_t lB[128 * 64];
    const int tid = threadIdx.x;
    const int w = tid >> 6;
    const int lane = tid & 63;
    const int wr = w >> 1, wc = w & 1;
    const int m0 = blockIdx.x * 128;
    const int n0 = blockIdx.y * 128;

    const int sr = lane >> 3;
    const int sj = lane & 7;

    f32x4 acc[4][4];
#pragma unroll
    for (int m = 0; m < 4; ++m)
#pragma unroll
        for (int n = 0; n < 4; ++n) acc[m][n] = (f32x4){0.f, 0.f, 0.f, 0.f};

    const char* Bb = (const char*)Bt;

    // A f32 staging geometry: thread covers row=tid>>1, 32 cols at ch*32
    const int arow = tid >> 1;
    const int ach = tid & 1;
    int agr = m0 + arow;
    if (AF32 && agr >= N_NODES) agr = 0;  // clamp: x has exactly N_NODES rows

    for (int kt = 0; kt < K / 64; ++kt) {
        if (AF32) {
            const float* Af = (const float*)Av;
            const float4* ap =
                (const float4*)(Af + (size_t)agr * K + kt * 64 + ach * 32);
            float4 c4[8];
#pragma unroll
            for (int i = 0; i < 8; ++i) c4[i] = ap[i];
            // B async staging (independent of LDS A writes)
#pragma unroll
            for (int i = 0; i < 4; ++i) {
                const int r = w * 32 + i * 8 + sr;
                const char* g = Bb + ((size_t)(n0 + r) * K + kt * 64) * 2 +
                                ((size_t)(sj ^ (r & 7)) << 4);
                async_copy16(g, lB + (size_t)(w * 32 + i * 8) * 64);
            }
            // convert + swizzled LDS write (4 x ds_write_b128)
#pragma unroll
            for (int i = 0; i < 4; ++i) {
                short8 o;
#pragma unroll
                for (int k = 0; k < 4; ++k) {
                    const float4 v = c4[i * 2 + k / 4];  // dummy, replaced below
                }
                const float4 va = c4[i * 2 + 0];
                const float4 vb = c4[i * 2 + 1];
                o[0] = (short)f2bf(va.x); o[1] = (short)f2bf(va.y);
                o[2] = (short)f2bf(va.z); o[3] = (short)f2bf(va.w);
                o[4] = (short)f2bf(vb.x); o[5] = (short)f2bf(vb.y);
                o[6] = (short)f2bf(vb.z); o[7] = (short)f2bf(vb.w);
                const int slot = (ach * 4 + i) ^ (arow & 7);
                *(short8*)((char*)lA + arow * 128 + slot * 16) = o;
            }
        } else {
            const char* Ab = (const char*)Av;
#pragma unroll
            for (int i = 0; i < 4; ++i) {
                const int r = w * 32 + i * 8 + sr;
                const char* g = Ab + ((size_t)(m0 + r) * K + kt * 64) * 2 +
                                ((size_t)(sj ^ (r & 7)) << 4);
                async_copy16(g, lA + (size_t)(w * 32 + i * 8) * 64);
            }
#pragma unroll
            for (int i = 0; i < 4; ++i) {
                const int r = w * 32 + i * 8 + sr;
                const char* g = Bb + ((size_t)(n0 + r) * K + kt * 64) * 2 +
                                ((size_t)(sj ^ (r & 7)) << 4);
                async_copy16(g, lB + (size_t)(w * 32 + i * 8) * 64);
            }
        }
        __syncthreads();

        const int g = lane >> 4;
        const int rr = lane & 15;
#pragma unroll
        for (int kk = 0; kk < 2; ++kk) {
            short8 av[4], bv[4];
#pragma unroll
            for (int m = 0; m < 4; ++m) {
                const int row = wr * 64 + m * 16 + rr;
                const int slot = (kk * 4 + g) ^ (row & 7);
                av[m] = *(const short8*)((const char*)lA + row * 128 + slot * 16);
            }
#pragma unroll
            for (int n = 0; n < 4; ++n) {
                const int row = wc * 64 + n * 16 + rr;
                const int slot = (kk * 4 + g) ^ (row & 7);
                bv[n] = *(const short8*)((const char*)lB + row * 128 + slot * 16);
            }
#pragma unroll
            for (int m = 0; m < 4; ++m)
#pragma unroll
                for (int n = 0; n < 4; ++n)
                    acc[m][n] = __builtin_amdgcn_mfma_f32_16x16x32_bf16(
                        av[m], bv[n], acc[m][n], 0, 0, 0);
        }
        __syncthreads();
    }

    const int rr = lane & 15;
    const int rg = lane >> 4;
#pragma unroll
    for (int m = 0; m < 4; ++m)
#pragma unroll
        for (int n = 0; n < 4; ++n)
#pragma unroll
            for (int q = 0; q < 4; ++q) {
                const int row = m0 + wr * 64 + m * 16 + rg * 4 + q;
                const int col = n0 + wc * 64 + n * 16 + rr;
                C[(size_t)row * N + col] = f2bf(acc[m][n][q]);
            }
}

// ---------------------------------------------------------------------------
// Gather: 16-deep pipelined chunks. MASKED variant predicates the accumulate
// (loads are always safe: csr_src padded with index 0).
// ---------------------------------------------------------------------------
template <int D, bool MASKED>
__device__ __forceinline__ void chunk16(const ushort_t* __restrict__ S,
                                        const int* __restrict__ csr,
                                        int j, int end, size_t coff,
                                        float* __restrict__ acc) {
    int id[16];
#pragma unroll
    for (int q = 0; q < 16; ++q) id[q] = csr[j + q];
    short8 v[16];
#pragma unroll
    for (int q = 0; q < 16; ++q)
        v[q] = *(const short8*)(S + (size_t)id[q] * D + coff);
#pragma unroll
    for (int q = 0; q < 16; ++q) {
        if (MASKED) {
            const float mq = (j + q < end) ? 1.f : 0.f;
#pragma unroll
            for (int k = 0; k < 8; ++k)
                acc[k] = fmaf(mq, bf2f((ushort_t)v[q][k]), acc[k]);
        } else {
#pragma unroll
            for (int k = 0; k < 8; ++k) acc[k] += bf2f((ushort_t)v[q][k]);
        }
    }
}

template <int D, bool OUT_BF16>
__global__ __launch_bounds__(256) void gather_bias_relu(
    const ushort_t* __restrict__ S, const int* __restrict__ rowptr,
    const int* __restrict__ csr_src, const float* __restrict__ bias,
    void* __restrict__ out) {
    constexpr int LPN = D / 8;
    const int gtid = blockIdx.x * blockDim.x + threadIdx.x;
    const int node = gtid / LPN;
    const int l = gtid % LPN;
    if (node >= N_NODES) return;
    const int beg = rowptr[node];
    const int end = rowptr[node + 1];
    const size_t coff = 8 * (size_t)l;

    float acc[8];
#pragma unroll
    for (int k = 0; k < 8; ++k) acc[k] = 0.f;

    const int nfull = (end - beg) & ~15;
    int j = beg;
    for (; j < beg + nfull; j += 16)
        chunk16<D, false>(S, csr_src, j, end, coff, acc);
    if (j < end)
        chunk16<D, true>(S, csr_src, j, end, coff, acc);

#pragma unroll
    for (int k = 0; k < 8; ++k) acc[k] = fmaxf(acc[k] + bias[coff + k], 0.f);

    if (OUT_BF16) {
        short8 o;
#pragma unroll
        for (int k = 0; k < 8; ++k) o[k] = (short)f2bf(acc[k]);
        *(short8*)((ushort_t*)out + (size_t)node * D + coff) = o;
    } else {
        float* op = (float*)out + (size_t)node * D + coff;
        *(float4*)(op + 0) = make_float4(acc[0], acc[1], acc[2], acc[3]);
        *(float4*)(op + 4) = make_float4(acc[4], acc[5], acc[6], acc[7]);
    }
}

// ---------------------------------------------------------------------------
extern "C" void kernel_launch(void* const* d_in, const int* in_sizes, int n_in,
                              void* d_out, int out_size, void* d_ws, size_t ws_size,
                              hipStream_t stream) {
    const float* x  = (const float*)d_in[0];
    const int*   eg = (const int*)d_in[1];
    const float* W1 = (const float*)d_in[2];
    const float* b1 = (const float*)d_in[3];
    const float* W2 = (const float*)d_in[4];
    const float* b2 = (const float*)d_in[5];
    float* out = (float*)d_out;

    char* ws = (char*)d_ws;
    const size_t SUP1_OFF = 0;              // MP*256*2 = 25,690,112
    const size_t AGG1_OFF = 25690112;       // MP*256*2
    const size_t SUP2_OFF = 51380224;       // MP*128*2
    const size_t W1T_OFF  = 77070336;       // 262,144
    const size_t W2T_OFF  = 77332480;       // 65,536
    const size_t RP_OFF   = 77398016;       // 50001*4 (pad to 200,016)
    const size_t CUR_OFF  = 77598032;       // 200,000
    const size_t CSR_OFF  = 77798032;       // 800016*4 = 3,200,064
    const size_t BSUM_OFF = 80998096;       // 196*4  (end ~81.0 MB)

    ushort_t* sup1 = (ushort_t*)(ws + SUP1_OFF);
    ushort_t* agg1 = (ushort_t*)(ws + AGG1_OFF);
    ushort_t* sup2 = (ushort_t*)(ws + SUP2_OFF);
    ushort_t* W1t  = (ushort_t*)(ws + W1T_OFF);
    ushort_t* W2t  = (ushort_t*)(ws + W2T_OFF);
    int* rowptr  = (int*)(ws + RP_OFF);
    int* cur     = (int*)(ws + CUR_OFF);
    int* csr_src = (int*)(ws + CSR_OFF);
    int* bsum    = (int*)(ws + BSUM_OFF);

    const int SCAN_BLKS = (N_NODES + 255) / 256;  // 196

    prep<<<512, 256, 0, stream>>>(W1, W2, W1t, W2t, rowptr, csr_src);

    // ---- CSR build ----
    edge_hist<<<(N_EDGES + 255) / 256, 256, 0, stream>>>(eg, rowptr);
    scan_blocks<<<SCAN_BLKS, 256, 0, stream>>>(rowptr, bsum);
    add_offsets<<<SCAN_BLKS, 256, 0, stream>>>(rowptr, cur, bsum);
    csr_fill<<<(N_EDGES + 255) / 256, 256, 0, stream>>>(eg, cur, csr_src);

    // ---- layer 1 (A = x f32, fused convert) ----
    gemm_mfma<512, true><<<dim3(MP / 128, 2), 256, 0, stream>>>(x, W1t, sup1, 256);
    gather_bias_relu<256, true><<<(N_NODES * 32 + 255) / 256, 256, 0, stream>>>(
        sup1, rowptr, csr_src, b1, agg1);

    // ---- layer 2 ----
    gemm_mfma<256, false><<<dim3(MP / 128, 1), 256, 0, stream>>>(agg1, W2t, sup2, 128);
    gather_bias_relu<128, false><<<(N_NODES * 16 + 255) / 256, 256, 0, stream>>>(
        sup2, rowptr, csr_src, b2, out);
}

// Round 6
// 229.947 us; speedup vs baseline: 19.0720x; 1.0755x over previous
//
#include <hip/hip_runtime.h>

#define N_NODES 50000
#define N_EDGES 800000
#define MP 50176  // 392 * 128, padded M for GEMM tiles

typedef unsigned short ushort_t;
typedef unsigned int uint_t;
using short8 = __attribute__((ext_vector_type(8))) short;
using f32x4 = __attribute__((ext_vector_type(4))) float;
using int4v = __attribute__((ext_vector_type(4))) int;

__device__ __forceinline__ ushort_t f2bf(float f) {
    uint_t u;
    __builtin_memcpy(&u, &f, 4);
    u = u + 0x7FFF + ((u >> 16) & 1);  // RNE
    return (ushort_t)(u >> 16);
}

__device__ __forceinline__ float bf2f(ushort_t h) {
    uint_t u = ((uint_t)h) << 16;
    float f;
    __builtin_memcpy(&f, &u, 4);
    return f;
}

// ---------------------------------------------------------------------------
// prep: zero rowptr + pad csr_src + transpose both W to bf16.
// ---------------------------------------------------------------------------
__global__ __launch_bounds__(256) void prep(const float* __restrict__ W1,
                                            const float* __restrict__ W2,
                                            ushort_t* __restrict__ W1t,
                                            ushort_t* __restrict__ W2t,
                                            int* __restrict__ rowptr,
                                            int* __restrict__ csr_src) {
    const int i = blockIdx.x * blockDim.x + threadIdx.x;
    if (i < 256 * 512) {               // W1t[n][k] = W1[k][n]
        const int n = i >> 9, k = i & 511;
        W1t[i] = f2bf(W1[(size_t)k * 256 + n]);
    }
    if (i < 128 * 256) {               // W2t[n][k] = W2[k][n]
        const int n = i >> 8, k = i & 255;
        W2t[i] = f2bf(W2[(size_t)k * 128 + n]);
    }
    if (i <= N_NODES) rowptr[i] = 0;
    if (i < 16) csr_src[N_EDGES + i] = 0;  // safe pad for masked gather chunks
}

// ---------------------------------------------------------------------------
// CSR build: hist -> per-block scan -> add block offsets -> fill.
// ---------------------------------------------------------------------------
__global__ void edge_hist(const int* __restrict__ eg, int* __restrict__ cnt) {
    const int e = blockIdx.x * blockDim.x + threadIdx.x;
    if (e >= N_EDGES) return;
    atomicAdd(&cnt[eg[N_EDGES + e]], 1);
}

__global__ __launch_bounds__(256) void scan_blocks(int* __restrict__ a,
                                                   int* __restrict__ bsum) {
    __shared__ int wsum[4];
    const int t = threadIdx.x, lane = t & 63, wid = t >> 6;
    const int i = blockIdx.x * 256 + t;
    const int v = (i < N_NODES) ? a[i] : 0;
    int s = v;
#pragma unroll
    for (int off = 1; off < 64; off <<= 1) {
        const int u = __shfl_up(s, off, 64);
        if (lane >= off) s += u;
    }
    if (lane == 63) wsum[wid] = s;
    __syncthreads();
    if (t == 0) {
        const int a0 = wsum[0], a1 = wsum[1], a2 = wsum[2], a3 = wsum[3];
        wsum[0] = 0; wsum[1] = a0; wsum[2] = a0 + a1; wsum[3] = a0 + a1 + a2;
        bsum[blockIdx.x] = a0 + a1 + a2 + a3;
    }
    __syncthreads();
    if (i < N_NODES) a[i] = wsum[wid] + s - v;
}

__global__ __launch_bounds__(256) void add_offsets(int* __restrict__ a,
                                                   int* __restrict__ cur,
                                                   const int* __restrict__ bsum) {
    __shared__ int off_s;
    const int t = threadIdx.x, b = blockIdx.x;
    if (t == 0) off_s = 0;
    __syncthreads();
    int partial = 0;
    for (int j = t; j < b; j += 256) partial += bsum[j];
#pragma unroll
    for (int off = 32; off >= 1; off >>= 1) partial += __shfl_down(partial, off, 64);
    if ((t & 63) == 0) atomicAdd(&off_s, partial);
    __syncthreads();
    const int off = off_s;
    const int i = b * 256 + t;
    if (i < N_NODES) { const int v = a[i] + off; a[i] = v; cur[i] = v; }
    if (b == gridDim.x - 1 && t == 0) a[N_NODES] = off + bsum[b];
}

__global__ void csr_fill(const int* __restrict__ eg, int* __restrict__ cur,
                         int* __restrict__ csr_src) {
    const int e = blockIdx.x * blockDim.x + threadIdx.x;
    if (e >= N_EDGES) return;
    const int d = eg[N_EDGES + e];
    const int p = atomicAdd(&cur[d], 1);
    csr_src[p] = eg[e];
}

// ---------------------------------------------------------------------------
// bf16 MFMA GEMM, 2-phase pipelined (T14): C[MP,BN] = A[MP,K] @ Bt[BN,K]^T.
// BM=64, BK=64, 8 waves (2m x 4n), wave tile 32 x (BN/4).
// All staging is reg-staged: issue global loads for tile kt+1 BEFORE the
// MFMA phase of tile kt (sched_barrier pins issue), ds_write after barrier.
// Single LDS buffer, XOR-swizzled 16B slots: slot ^= (row&7) on both sides.
// AF32: A is f32, converted to bf16 during staging (fused convert).
// ---------------------------------------------------------------------------
template <int K, int BN, bool AF32>
__global__ __launch_bounds__(512) void gemm_mfma(const void* __restrict__ Av,
                                                 const ushort_t* __restrict__ Bt,
                                                 ushort_t* __restrict__ C) {
    constexpr int KT = K / 64;
    constexpr int NF = BN / 64;               // n-frags per wave
    constexpr int BSL = (BN == 256) ? 4 : 2;  // B slots per thread
    __shared__ ushort_t lA[64 * 64];
    __shared__ ushort_t lB[BN * 64];
    const int tid = threadIdx.x;
    const int w = tid >> 6, lane = tid & 63;
    const int wr = w >> 2, wc = w & 3;
    const int m0 = blockIdx.x * 64;

    // A staging: 64 rows x 8 slots = 512 threads -> 1 slot (16B bf16) each
    const int ar = tid >> 3, aq = tid & 7;
    // B staging: BN x 8 slots / 512 threads -> BSL slots each
    const int br = (BN == 256) ? (tid >> 1) : (tid >> 2);
    const int bs0 = (BN == 256) ? ((tid & 1) * 4) : ((tid & 3) * 2);

    int agr = m0 + ar;
    if (AF32 && agr >= N_NODES) agr = 0;  // x has exactly N_NODES rows

    f32x4 acc[2][NF];
#pragma unroll
    for (int m = 0; m < 2; ++m)
#pragma unroll
        for (int n = 0; n < NF; ++n) acc[m][n] = (f32x4){0.f, 0.f, 0.f, 0.f};

    float4 rAf0, rAf1;  // AF32 staging regs (8 floats)
    int4v rAh;          // bf16 staging reg (8 bf16)
    int4v rB[BSL];

    auto LOAD = [&](int kt) {
        if constexpr (AF32) {
            const float* Af = (const float*)Av;
            const float4* p = (const float4*)(Af + (size_t)agr * K + kt * 64 + aq * 8);
            rAf0 = p[0];
            rAf1 = p[1];
        } else {
            const ushort_t* Ab = (const ushort_t*)Av;
            rAh = *(const int4v*)(Ab + (size_t)(m0 + ar) * K + kt * 64 + aq * 8);
        }
        const int4v* qp = (const int4v*)(Bt + (size_t)br * K + kt * 64 + bs0 * 8);
#pragma unroll
        for (int s = 0; s < BSL; ++s) rB[s] = qp[s];
    };

    auto STORE = [&]() {
        short8 oa;
        if constexpr (AF32) {
            oa[0] = (short)f2bf(rAf0.x); oa[1] = (short)f2bf(rAf0.y);
            oa[2] = (short)f2bf(rAf0.z); oa[3] = (short)f2bf(rAf0.w);
            oa[4] = (short)f2bf(rAf1.x); oa[5] = (short)f2bf(rAf1.y);
            oa[6] = (short)f2bf(rAf1.z); oa[7] = (short)f2bf(rAf1.w);
        } else {
            __builtin_memcpy(&oa, &rAh, 16);
        }
        *(short8*)((char*)lA + ar * 128 + ((aq ^ (ar & 7)) << 4)) = oa;
#pragma unroll
        for (int s = 0; s < BSL; ++s) {
            short8 ob;
            __builtin_memcpy(&ob, &rB[s], 16);
            *(short8*)((char*)lB + br * 128 + (((bs0 + s) ^ (br & 7)) << 4)) = ob;
        }
    };

    LOAD(0);
    STORE();
    __syncthreads();

    for (int kt = 0; kt < KT; ++kt) {
        if (kt + 1 < KT) LOAD(kt + 1);          // prefetch next tile to regs
        __builtin_amdgcn_sched_barrier(0);      // pin issue before compute
        const int g = lane >> 4, rr = lane & 15;
#pragma unroll
        for (int kk = 0; kk < 2; ++kk) {
            short8 av[2], bv[NF];
#pragma unroll
            for (int m = 0; m < 2; ++m) {
                const int row = wr * 32 + m * 16 + rr;
                av[m] = *(const short8*)((const char*)lA + row * 128 +
                                         (((kk * 4 + g) ^ (row & 7)) << 4));
            }
#pragma unroll
            for (int n = 0; n < NF; ++n) {
                const int row = wc * (BN / 4) + n * 16 + rr;
                bv[n] = *(const short8*)((const char*)lB + row * 128 +
                                         (((kk * 4 + g) ^ (row & 7)) << 4));
            }
#pragma unroll
            for (int m = 0; m < 2; ++m)
#pragma unroll
                for (int n = 0; n < NF; ++n)
                    acc[m][n] = __builtin_amdgcn_mfma_f32_16x16x32_bf16(
                        av[m], bv[n], acc[m][n], 0, 0, 0);
        }
        __syncthreads();
        if (kt + 1 < KT) {
            STORE();  // waits on prefetched loads; latency hidden under MFMA
            __syncthreads();
        }
    }

    const int rr = lane & 15, rg = lane >> 4;
#pragma unroll
    for (int m = 0; m < 2; ++m)
#pragma unroll
        for (int n = 0; n < NF; ++n)
#pragma unroll
            for (int q = 0; q < 4; ++q) {
                const int row = m0 + wr * 32 + m * 16 + rg * 4 + q;
                const int col = wc * (BN / 4) + n * 16 + rr;
                C[(size_t)row * BN + col] = f2bf(acc[m][n][q]);
            }
}

// ---------------------------------------------------------------------------
// Gather: full 16-chunks + unmasked 8-chunk + masked 8-chunk tail.
// Loads always safe: csr_src padded with index 0.
// ---------------------------------------------------------------------------
template <int D, int CH, bool MASKED>
__device__ __forceinline__ void chunkN(const ushort_t* __restrict__ S,
                                       const int* __restrict__ csr,
                                       int j, int end, size_t coff,
                                       float* __restrict__ acc) {
    int id[CH];
#pragma unroll
    for (int q = 0; q < CH; ++q) id[q] = csr[j + q];
    short8 v[CH];
#pragma unroll
    for (int q = 0; q < CH; ++q)
        v[q] = *(const short8*)(S + (size_t)id[q] * D + coff);
#pragma unroll
    for (int q = 0; q < CH; ++q) {
        if (MASKED) {
            const float mq = (j + q < end) ? 1.f : 0.f;
#pragma unroll
            for (int k = 0; k < 8; ++k)
                acc[k] = fmaf(mq, bf2f((ushort_t)v[q][k]), acc[k]);
        } else {
#pragma unroll
            for (int k = 0; k < 8; ++k) acc[k] += bf2f((ushort_t)v[q][k]);
        }
    }
}

template <int D, bool OUT_BF16>
__global__ __launch_bounds__(256) void gather_bias_relu(
    const ushort_t* __restrict__ S, const int* __restrict__ rowptr,
    const int* __restrict__ csr_src, const float* __restrict__ bias,
    void* __restrict__ out) {
    constexpr int LPN = D / 8;
    const int gtid = blockIdx.x * blockDim.x + threadIdx.x;
    const int node = gtid / LPN;
    const int l = gtid % LPN;
    if (node >= N_NODES) return;
    const int beg = rowptr[node];
    const int end = rowptr[node + 1];
    const size_t coff = 8 * (size_t)l;

    float acc[8];
#pragma unroll
    for (int k = 0; k < 8; ++k) acc[k] = 0.f;

    const int deg = end - beg;
    int j = beg;
    const int e16 = beg + (deg & ~15);
    for (; j < e16; j += 16) chunkN<D, 16, false>(S, csr_src, j, end, coff, acc);
    if (deg & 8) {
        chunkN<D, 8, false>(S, csr_src, j, end, coff, acc);
        j += 8;
    }
    if (j < end) chunkN<D, 8, true>(S, csr_src, j, end, coff, acc);

#pragma unroll
    for (int k = 0; k < 8; ++k) acc[k] = fmaxf(acc[k] + bias[coff + k], 0.f);

    if (OUT_BF16) {
        short8 o;
#pragma unroll
        for (int k = 0; k < 8; ++k) o[k] = (short)f2bf(acc[k]);
        *(short8*)((ushort_t*)out + (size_t)node * D + coff) = o;
    } else {
        float* op = (float*)out + (size_t)node * D + coff;
        *(float4*)(op + 0) = make_float4(acc[0], acc[1], acc[2], acc[3]);
        *(float4*)(op + 4) = make_float4(acc[4], acc[5], acc[6], acc[7]);
    }
}

// ---------------------------------------------------------------------------
extern "C" void kernel_launch(void* const* d_in, const int* in_sizes, int n_in,
                              void* d_out, int out_size, void* d_ws, size_t ws_size,
                              hipStream_t stream) {
    const float* x  = (const float*)d_in[0];
    const int*   eg = (const int*)d_in[1];
    const float* W1 = (const float*)d_in[2];
    const float* b1 = (const float*)d_in[3];
    const float* W2 = (const float*)d_in[4];
    const float* b2 = (const float*)d_in[5];
    float* out = (float*)d_out;

    char* ws = (char*)d_ws;
    const size_t SUP1_OFF = 0;              // MP*256*2 = 25,690,112
    const size_t AGG1_OFF = 25690112;       // MP*256*2
    const size_t SUP2_OFF = 51380224;       // MP*128*2
    const size_t W1T_OFF  = 77070336;       // 262,144
    const size_t W2T_OFF  = 77332480;       // 65,536
    const size_t RP_OFF   = 77398016;       // 50001*4 (pad to 200,016)
    const size_t CUR_OFF  = 77598032;       // 200,000
    const size_t CSR_OFF  = 77798032;       // 800016*4 = 3,200,064
    const size_t BSUM_OFF = 80998096;       // 196*4  (end ~81.0 MB)

    ushort_t* sup1 = (ushort_t*)(ws + SUP1_OFF);
    ushort_t* agg1 = (ushort_t*)(ws + AGG1_OFF);
    ushort_t* sup2 = (ushort_t*)(ws + SUP2_OFF);
    ushort_t* W1t  = (ushort_t*)(ws + W1T_OFF);
    ushort_t* W2t  = (ushort_t*)(ws + W2T_OFF);
    int* rowptr  = (int*)(ws + RP_OFF);
    int* cur     = (int*)(ws + CUR_OFF);
    int* csr_src = (int*)(ws + CSR_OFF);
    int* bsum    = (int*)(ws + BSUM_OFF);

    const int SCAN_BLKS = (N_NODES + 255) / 256;  // 196

    prep<<<512, 256, 0, stream>>>(W1, W2, W1t, W2t, rowptr, csr_src);

    // ---- CSR build ----
    edge_hist<<<(N_EDGES + 255) / 256, 256, 0, stream>>>(eg, rowptr);
    scan_blocks<<<SCAN_BLKS, 256, 0, stream>>>(rowptr, bsum);
    add_offsets<<<SCAN_BLKS, 256, 0, stream>>>(rowptr, cur, bsum);
    csr_fill<<<(N_EDGES + 255) / 256, 256, 0, stream>>>(eg, cur, csr_src);

    // ---- layer 1 (A = x f32, fused convert) ----
    gemm_mfma<512, 256, true><<<MP / 64, 512, 0, stream>>>(x, W1t, sup1);
    gather_bias_relu<256, true><<<(N_NODES * 32 + 255) / 256, 256, 0, stream>>>(
        sup1, rowptr, csr_src, b1, agg1);

    // ---- layer 2 ----
    gemm_mfma<256, 128, false><<<MP / 64, 512, 0, stream>>>(agg1, W2t, sup2);
    gather_bias_relu<128, false><<<(N_NODES * 16 + 255) / 256, 256, 0, stream>>>(
        sup2, rowptr, csr_src, b2, out);
}

// Round 7
// 214.867 us; speedup vs baseline: 20.4106x; 1.0702x over previous
//
#include <hip/hip_runtime.h>
#include <hip/hip_fp8.h>

#define N_NODES 50000
#define N_EDGES 800000
#define MP 50176  // 392 * 128, padded M for GEMM tiles

typedef unsigned short ushort_t;
typedef unsigned int uint_t;
using short8 = __attribute__((ext_vector_type(8))) short;
using f32x4 = __attribute__((ext_vector_type(4))) float;
using int4v = __attribute__((ext_vector_type(4))) int;
using uint4v = __attribute__((ext_vector_type(4))) uint_t;

__device__ __forceinline__ ushort_t f2bf(float f) {
    uint_t u;
    __builtin_memcpy(&u, &f, 4);
    u = u + 0x7FFF + ((u >> 16) & 1);  // RNE
    return (ushort_t)(u >> 16);
}

__device__ __forceinline__ float bf2f(ushort_t h) {
    uint_t u = ((uint_t)h) << 16;
    float f;
    __builtin_memcpy(&f, &u, 4);
    return f;
}

__device__ __forceinline__ float fp8_to_f32(unsigned char b) {
    const __hip_fp8_e4m3 h = __builtin_bit_cast(__hip_fp8_e4m3, b);
    return (float)h;
}

__device__ __forceinline__ unsigned char f32_to_fp8(float v) {
    return (unsigned char)__hip_fp8_e4m3(v).__x;
}

// ---------------------------------------------------------------------------
// prep: zero rowptr + pad csr_src + transpose both W to bf16.
// ---------------------------------------------------------------------------
__global__ __launch_bounds__(256) void prep(const float* __restrict__ W1,
                                            const float* __restrict__ W2,
                                            ushort_t* __restrict__ W1t,
                                            ushort_t* __restrict__ W2t,
                                            int* __restrict__ rowptr,
                                            int* __restrict__ csr_src) {
    const int i = blockIdx.x * blockDim.x + threadIdx.x;
    if (i < 256 * 512) {               // W1t[n][k] = W1[k][n]
        const int n = i >> 9, k = i & 511;
        W1t[i] = f2bf(W1[(size_t)k * 256 + n]);
    }
    if (i < 128 * 256) {               // W2t[n][k] = W2[k][n]
        const int n = i >> 8, k = i & 255;
        W2t[i] = f2bf(W2[(size_t)k * 128 + n]);
    }
    if (i <= N_NODES) rowptr[i] = 0;
    if (i < 16) csr_src[N_EDGES + i] = 0;  // safe pad for masked gather chunks
}

// ---------------------------------------------------------------------------
// CSR build: hist -> per-block scan -> add block offsets -> fill.
// ---------------------------------------------------------------------------
__global__ void edge_hist(const int* __restrict__ eg, int* __restrict__ cnt) {
    const int e = blockIdx.x * blockDim.x + threadIdx.x;
    if (e >= N_EDGES) return;
    atomicAdd(&cnt[eg[N_EDGES + e]], 1);
}

__global__ __launch_bounds__(256) void scan_blocks(int* __restrict__ a,
                                                   int* __restrict__ bsum) {
    __shared__ int wsum[4];
    const int t = threadIdx.x, lane = t & 63, wid = t >> 6;
    const int i = blockIdx.x * 256 + t;
    const int v = (i < N_NODES) ? a[i] : 0;
    int s = v;
#pragma unroll
    for (int off = 1; off < 64; off <<= 1) {
        const int u = __shfl_up(s, off, 64);
        if (lane >= off) s += u;
    }
    if (lane == 63) wsum[wid] = s;
    __syncthreads();
    if (t == 0) {
        const int a0 = wsum[0], a1 = wsum[1], a2 = wsum[2], a3 = wsum[3];
        wsum[0] = 0; wsum[1] = a0; wsum[2] = a0 + a1; wsum[3] = a0 + a1 + a2;
        bsum[blockIdx.x] = a0 + a1 + a2 + a3;
    }
    __syncthreads();
    if (i < N_NODES) a[i] = wsum[wid] + s - v;
}

__global__ __launch_bounds__(256) void add_offsets(int* __restrict__ a,
                                                   int* __restrict__ cur,
                                                   const int* __restrict__ bsum) {
    __shared__ int off_s;
    const int t = threadIdx.x, b = blockIdx.x;
    if (t == 0) off_s = 0;
    __syncthreads();
    int partial = 0;
    for (int j = t; j < b; j += 256) partial += bsum[j];
#pragma unroll
    for (int off = 32; off >= 1; off >>= 1) partial += __shfl_down(partial, off, 64);
    if ((t & 63) == 0) atomicAdd(&off_s, partial);
    __syncthreads();
    const int off = off_s;
    const int i = b * 256 + t;
    if (i < N_NODES) { const int v = a[i] + off; a[i] = v; cur[i] = v; }
    if (b == gridDim.x - 1 && t == 0) a[N_NODES] = off + bsum[b];
}

__global__ void csr_fill(const int* __restrict__ eg, int* __restrict__ cur,
                         int* __restrict__ csr_src) {
    const int e = blockIdx.x * blockDim.x + threadIdx.x;
    if (e >= N_EDGES) return;
    const int d = eg[N_EDGES + e];
    const int p = atomicAdd(&cur[d], 1);
    csr_src[p] = eg[e];
}

// ---------------------------------------------------------------------------
// bf16 MFMA GEMM, 2-phase pipelined (T14): C[MP,BN] = A[MP,K] @ Bt[BN,K]^T.
// BM=64, BK=64, 8 waves (2m x 4n). Reg-staged prefetch; single LDS buffer,
// XOR-swizzled 16B slots. AF32: A f32->bf16 fused. CFP8: C stored fp8 e4m3.
// ---------------------------------------------------------------------------
template <int K, int BN, bool AF32, bool CFP8>
__global__ __launch_bounds__(512) void gemm_mfma(const void* __restrict__ Av,
                                                 const ushort_t* __restrict__ Bt,
                                                 void* __restrict__ Cv) {
    constexpr int KT = K / 64;
    constexpr int NF = BN / 64;               // n-frags per wave
    constexpr int BSL = (BN == 256) ? 4 : 2;  // B slots per thread
    __shared__ ushort_t lA[64 * 64];
    __shared__ ushort_t lB[BN * 64];
    const int tid = threadIdx.x;
    const int w = tid >> 6, lane = tid & 63;
    const int wr = w >> 2, wc = w & 3;
    const int m0 = blockIdx.x * 64;

    const int ar = tid >> 3, aq = tid & 7;
    const int br = (BN == 256) ? (tid >> 1) : (tid >> 2);
    const int bs0 = (BN == 256) ? ((tid & 1) * 4) : ((tid & 3) * 2);

    int agr = m0 + ar;
    if (AF32 && agr >= N_NODES) agr = 0;  // x has exactly N_NODES rows

    f32x4 acc[2][NF];
#pragma unroll
    for (int m = 0; m < 2; ++m)
#pragma unroll
        for (int n = 0; n < NF; ++n) acc[m][n] = (f32x4){0.f, 0.f, 0.f, 0.f};

    float4 rAf0, rAf1;
    int4v rAh;
    int4v rB[BSL];

    auto LOAD = [&](int kt) {
        if constexpr (AF32) {
            const float* Af = (const float*)Av;
            const float4* p = (const float4*)(Af + (size_t)agr * K + kt * 64 + aq * 8);
            rAf0 = p[0];
            rAf1 = p[1];
        } else {
            const ushort_t* Ab = (const ushort_t*)Av;
            rAh = *(const int4v*)(Ab + (size_t)(m0 + ar) * K + kt * 64 + aq * 8);
        }
        const int4v* qp = (const int4v*)(Bt + (size_t)br * K + kt * 64 + bs0 * 8);
#pragma unroll
        for (int s = 0; s < BSL; ++s) rB[s] = qp[s];
    };

    auto STORE = [&]() {
        short8 oa;
        if constexpr (AF32) {
            oa[0] = (short)f2bf(rAf0.x); oa[1] = (short)f2bf(rAf0.y);
            oa[2] = (short)f2bf(rAf0.z); oa[3] = (short)f2bf(rAf0.w);
            oa[4] = (short)f2bf(rAf1.x); oa[5] = (short)f2bf(rAf1.y);
            oa[6] = (short)f2bf(rAf1.z); oa[7] = (short)f2bf(rAf1.w);
        } else {
            __builtin_memcpy(&oa, &rAh, 16);
        }
        *(short8*)((char*)lA + ar * 128 + ((aq ^ (ar & 7)) << 4)) = oa;
#pragma unroll
        for (int s = 0; s < BSL; ++s) {
            short8 ob;
            __builtin_memcpy(&ob, &rB[s], 16);
            *(short8*)((char*)lB + br * 128 + (((bs0 + s) ^ (br & 7)) << 4)) = ob;
        }
    };

    LOAD(0);
    STORE();
    __syncthreads();

    for (int kt = 0; kt < KT; ++kt) {
        if (kt + 1 < KT) LOAD(kt + 1);          // prefetch next tile to regs
        __builtin_amdgcn_sched_barrier(0);      // pin issue before compute
        const int g = lane >> 4, rr = lane & 15;
#pragma unroll
        for (int kk = 0; kk < 2; ++kk) {
            short8 av[2], bv[NF];
#pragma unroll
            for (int m = 0; m < 2; ++m) {
                const int row = wr * 32 + m * 16 + rr;
                av[m] = *(const short8*)((const char*)lA + row * 128 +
                                         (((kk * 4 + g) ^ (row & 7)) << 4));
            }
#pragma unroll
            for (int n = 0; n < NF; ++n) {
                const int row = wc * (BN / 4) + n * 16 + rr;
                bv[n] = *(const short8*)((const char*)lB + row * 128 +
                                         (((kk * 4 + g) ^ (row & 7)) << 4));
            }
#pragma unroll
            for (int m = 0; m < 2; ++m)
#pragma unroll
                for (int n = 0; n < NF; ++n)
                    acc[m][n] = __builtin_amdgcn_mfma_f32_16x16x32_bf16(
                        av[m], bv[n], acc[m][n], 0, 0, 0);
        }
        __syncthreads();
        if (kt + 1 < KT) {
            STORE();  // waits on prefetched loads; latency hidden under MFMA
            __syncthreads();
        }
    }

    const int rr = lane & 15, rg = lane >> 4;
#pragma unroll
    for (int m = 0; m < 2; ++m)
#pragma unroll
        for (int n = 0; n < NF; ++n)
#pragma unroll
            for (int q = 0; q < 4; ++q) {
                const int row = m0 + wr * 32 + m * 16 + rg * 4 + q;
                const int col = wc * (BN / 4) + n * 16 + rr;
                if constexpr (CFP8) {
                    ((unsigned char*)Cv)[(size_t)row * BN + col] =
                        f32_to_fp8(acc[m][n][q]);
                } else {
                    ((ushort_t*)Cv)[(size_t)row * BN + col] = f2bf(acc[m][n][q]);
                }
            }
}

// ---------------------------------------------------------------------------
// Layer-1 gather over fp8 support (row = 256 fp8 = 256B) + bias + ReLU,
// bf16 output. 16 lanes/node, 16 fp8 (16B) per lane per edge, 8-deep chunks.
// ---------------------------------------------------------------------------
template <bool MASKED>
__device__ __forceinline__ void chunk8_fp8(const unsigned char* __restrict__ S,
                                           const int* __restrict__ csr,
                                           int j, int end, int coff,
                                           float* __restrict__ acc) {
    int id[8];
#pragma unroll
    for (int q = 0; q < 8; ++q) id[q] = csr[j + q];
    uint4v v[8];
#pragma unroll
    for (int q = 0; q < 8; ++q)
        v[q] = *(const uint4v*)(S + (size_t)id[q] * 256 + coff);
#pragma unroll
    for (int q = 0; q < 8; ++q) {
        const float mq = MASKED ? ((j + q < end) ? 1.f : 0.f) : 1.f;
#pragma unroll
        for (int wd = 0; wd < 4; ++wd) {
            const uint_t word = v[q][wd];
#pragma unroll
            for (int b = 0; b < 4; ++b) {
                const float f = fp8_to_f32((unsigned char)((word >> (8 * b)) & 0xFF));
                if (MASKED)
                    acc[wd * 4 + b] = fmaf(mq, f, acc[wd * 4 + b]);
                else
                    acc[wd * 4 + b] += f;
            }
        }
    }
}

__global__ __launch_bounds__(256) void gather1_fp8(
    const unsigned char* __restrict__ S, const int* __restrict__ rowptr,
    const int* __restrict__ csr_src, const float* __restrict__ bias,
    ushort_t* __restrict__ out) {
    const int gtid = blockIdx.x * blockDim.x + threadIdx.x;
    const int node = gtid >> 4;
    const int l = gtid & 15;
    if (node >= N_NODES) return;
    const int beg = rowptr[node];
    const int end = rowptr[node + 1];
    const int coff = l * 16;

    float acc[16];
#pragma unroll
    for (int k = 0; k < 16; ++k) acc[k] = 0.f;

    const int deg = end - beg;
    int j = beg;
    const int e8 = beg + (deg & ~7);
    for (; j < e8; j += 8) chunk8_fp8<false>(S, csr_src, j, end, coff, acc);
    if (j < end) chunk8_fp8<true>(S, csr_src, j, end, coff, acc);

#pragma unroll
    for (int k = 0; k < 16; ++k) acc[k] = fmaxf(acc[k] + bias[coff + k], 0.f);

    short8 o0, o1;
#pragma unroll
    for (int k = 0; k < 8; ++k) {
        o0[k] = (short)f2bf(acc[k]);
        o1[k] = (short)f2bf(acc[8 + k]);
    }
    ushort_t* op = out + (size_t)node * 256 + coff;
    *(short8*)(op) = o0;
    *(short8*)(op + 8) = o1;
}

// ---------------------------------------------------------------------------
// Layer-2 gather (bf16 support): full 16-chunks + 8 + masked-8 tail.
// ---------------------------------------------------------------------------
template <int D, int CH, bool MASKED>
__device__ __forceinline__ void chunkN(const ushort_t* __restrict__ S,
                                       const int* __restrict__ csr,
                                       int j, int end, size_t coff,
                                       float* __restrict__ acc) {
    int id[CH];
#pragma unroll
    for (int q = 0; q < CH; ++q) id[q] = csr[j + q];
    short8 v[CH];
#pragma unroll
    for (int q = 0; q < CH; ++q)
        v[q] = *(const short8*)(S + (size_t)id[q] * D + coff);
#pragma unroll
    for (int q = 0; q < CH; ++q) {
        if (MASKED) {
            const float mq = (j + q < end) ? 1.f : 0.f;
#pragma unroll
            for (int k = 0; k < 8; ++k)
                acc[k] = fmaf(mq, bf2f((ushort_t)v[q][k]), acc[k]);
        } else {
#pragma unroll
            for (int k = 0; k < 8; ++k) acc[k] += bf2f((ushort_t)v[q][k]);
        }
    }
}

template <int D, bool OUT_BF16>
__global__ __launch_bounds__(256) void gather_bias_relu(
    const ushort_t* __restrict__ S, const int* __restrict__ rowptr,
    const int* __restrict__ csr_src, const float* __restrict__ bias,
    void* __restrict__ out) {
    constexpr int LPN = D / 8;
    const int gtid = blockIdx.x * blockDim.x + threadIdx.x;
    const int node = gtid / LPN;
    const int l = gtid % LPN;
    if (node >= N_NODES) return;
    const int beg = rowptr[node];
    const int end = rowptr[node + 1];
    const size_t coff = 8 * (size_t)l;

    float acc[8];
#pragma unroll
    for (int k = 0; k < 8; ++k) acc[k] = 0.f;

    const int deg = end - beg;
    int j = beg;
    const int e16 = beg + (deg & ~15);
    for (; j < e16; j += 16) chunkN<D, 16, false>(S, csr_src, j, end, coff, acc);
    if (deg & 8) {
        chunkN<D, 8, false>(S, csr_src, j, end, coff, acc);
        j += 8;
    }
    if (j < end) chunkN<D, 8, true>(S, csr_src, j, end, coff, acc);

#pragma unroll
    for (int k = 0; k < 8; ++k) acc[k] = fmaxf(acc[k] + bias[coff + k], 0.f);

    if (OUT_BF16) {
        short8 o;
#pragma unroll
        for (int k = 0; k < 8; ++k) o[k] = (short)f2bf(acc[k]);
        *(short8*)((ushort_t*)out + (size_t)node * D + coff) = o;
    } else {
        float* op = (float*)out + (size_t)node * D + coff;
        *(float4*)(op + 0) = make_float4(acc[0], acc[1], acc[2], acc[3]);
        *(float4*)(op + 4) = make_float4(acc[4], acc[5], acc[6], acc[7]);
    }
}

// ---------------------------------------------------------------------------
extern "C" void kernel_launch(void* const* d_in, const int* in_sizes, int n_in,
                              void* d_out, int out_size, void* d_ws, size_t ws_size,
                              hipStream_t stream) {
    const float* x  = (const float*)d_in[0];
    const int*   eg = (const int*)d_in[1];
    const float* W1 = (const float*)d_in[2];
    const float* b1 = (const float*)d_in[3];
    const float* W2 = (const float*)d_in[4];
    const float* b2 = (const float*)d_in[5];
    float* out = (float*)d_out;

    char* ws = (char*)d_ws;
    const size_t SUP1_OFF = 0;              // MP*256*1 (fp8) = 12,845,056
    const size_t AGG1_OFF = 25690112;       // MP*256*2 (bf16)
    const size_t SUP2_OFF = 51380224;       // MP*128*2 (bf16)
    const size_t W1T_OFF  = 77070336;       // 262,144
    const size_t W2T_OFF  = 77332480;       // 65,536
    const size_t RP_OFF   = 77398016;       // 50001*4 (pad to 200,016)
    const size_t CUR_OFF  = 77598032;       // 200,000
    const size_t CSR_OFF  = 77798032;       // 800016*4 = 3,200,064
    const size_t BSUM_OFF = 80998096;       // 196*4  (end ~81.0 MB)

    unsigned char* sup1 = (unsigned char*)(ws + SUP1_OFF);
    ushort_t* agg1 = (ushort_t*)(ws + AGG1_OFF);
    ushort_t* sup2 = (ushort_t*)(ws + SUP2_OFF);
    ushort_t* W1t  = (ushort_t*)(ws + W1T_OFF);
    ushort_t* W2t  = (ushort_t*)(ws + W2T_OFF);
    int* rowptr  = (int*)(ws + RP_OFF);
    int* cur     = (int*)(ws + CUR_OFF);
    int* csr_src = (int*)(ws + CSR_OFF);
    int* bsum    = (int*)(ws + BSUM_OFF);

    const int SCAN_BLKS = (N_NODES + 255) / 256;  // 196

    prep<<<512, 256, 0, stream>>>(W1, W2, W1t, W2t, rowptr, csr_src);

    // ---- CSR build ----
    edge_hist<<<(N_EDGES + 255) / 256, 256, 0, stream>>>(eg, rowptr);
    scan_blocks<<<SCAN_BLKS, 256, 0, stream>>>(rowptr, bsum);
    add_offsets<<<SCAN_BLKS, 256, 0, stream>>>(rowptr, cur, bsum);
    csr_fill<<<(N_EDGES + 255) / 256, 256, 0, stream>>>(eg, cur, csr_src);

    // ---- layer 1: gemm (A = x f32, fused convert; C = fp8) + fp8 gather ----
    gemm_mfma<512, 256, true, true><<<MP / 64, 512, 0, stream>>>(x, W1t, sup1);
    gather1_fp8<<<(N_NODES * 16 + 255) / 256, 256, 0, stream>>>(
        sup1, rowptr, csr_src, b1, agg1);

    // ---- layer 2 (bf16 throughout) ----
    gemm_mfma<256, 128, false, false><<<MP / 64, 512, 0, stream>>>(agg1, W2t, sup2);
    gather_bias_relu<128, false><<<(N_NODES * 16 + 255) / 256, 256, 0, stream>>>(
        sup2, rowptr, csr_src, b2, out);
}

// Round 8
// 203.612 us; speedup vs baseline: 21.5388x; 1.0553x over previous
//
#include <hip/hip_runtime.h>
#include <hip/hip_fp8.h>

#define N_NODES 50000
#define N_EDGES 800000
#define MP 50176  // 392 * 128, padded M for GEMM tiles

typedef unsigned short ushort_t;
typedef unsigned int uint_t;
using short8 = __attribute__((ext_vector_type(8))) short;
using f32x4 = __attribute__((ext_vector_type(4))) float;
using int4v = __attribute__((ext_vector_type(4))) int;
using uint4v = __attribute__((ext_vector_type(4))) uint_t;

__device__ __forceinline__ ushort_t f2bf(float f) {
    uint_t u;
    __builtin_memcpy(&u, &f, 4);
    u = u + 0x7FFF + ((u >> 16) & 1);  // RNE
    return (ushort_t)(u >> 16);
}

__device__ __forceinline__ float bf2f(ushort_t h) {
    uint_t u = ((uint_t)h) << 16;
    float f;
    __builtin_memcpy(&f, &u, 4);
    return f;
}

__device__ __forceinline__ float fp8_to_f32(unsigned char b) {
    const __hip_fp8_e4m3 h = __builtin_bit_cast(__hip_fp8_e4m3, b);
    return (float)h;
}

__device__ __forceinline__ unsigned char f32_to_fp8(float v) {
    return (unsigned char)__hip_fp8_e4m3(v).__x;
}

// ---------------------------------------------------------------------------
// prep: zero rowptr + pad csr_src + transpose both W to bf16.
// ---------------------------------------------------------------------------
__global__ __launch_bounds__(256) void prep(const float* __restrict__ W1,
                                            const float* __restrict__ W2,
                                            ushort_t* __restrict__ W1t,
                                            ushort_t* __restrict__ W2t,
                                            int* __restrict__ rowptr,
                                            int* __restrict__ csr_src) {
    const int i = blockIdx.x * blockDim.x + threadIdx.x;
    if (i < 256 * 512) {               // W1t[n][k] = W1[k][n]
        const int n = i >> 9, k = i & 511;
        W1t[i] = f2bf(W1[(size_t)k * 256 + n]);
    }
    if (i < 128 * 256) {               // W2t[n][k] = W2[k][n]
        const int n = i >> 8, k = i & 255;
        W2t[i] = f2bf(W2[(size_t)k * 128 + n]);
    }
    if (i <= N_NODES) rowptr[i] = 0;
    if (i < 16) csr_src[N_EDGES + i] = 0;  // safe pad for masked gather chunks
}

// ---------------------------------------------------------------------------
// CSR build: hist -> per-block scan -> add block offsets -> partitioned fill.
// ---------------------------------------------------------------------------
__global__ void edge_hist(const int* __restrict__ eg, int* __restrict__ cnt) {
    const int e = blockIdx.x * blockDim.x + threadIdx.x;
    if (e >= N_EDGES) return;
    atomicAdd(&cnt[eg[N_EDGES + e]], 1);
}

__global__ __launch_bounds__(256) void scan_blocks(int* __restrict__ a,
                                                   int* __restrict__ bsum) {
    __shared__ int wsum[4];
    const int t = threadIdx.x, lane = t & 63, wid = t >> 6;
    const int i = blockIdx.x * 256 + t;
    const int v = (i < N_NODES) ? a[i] : 0;
    int s = v;
#pragma unroll
    for (int off = 1; off < 64; off <<= 1) {
        const int u = __shfl_up(s, off, 64);
        if (lane >= off) s += u;
    }
    if (lane == 63) wsum[wid] = s;
    __syncthreads();
    if (t == 0) {
        const int a0 = wsum[0], a1 = wsum[1], a2 = wsum[2], a3 = wsum[3];
        wsum[0] = 0; wsum[1] = a0; wsum[2] = a0 + a1; wsum[3] = a0 + a1 + a2;
        bsum[blockIdx.x] = a0 + a1 + a2 + a3;
    }
    __syncthreads();
    if (i < N_NODES) a[i] = wsum[wid] + s - v;
}

__global__ __launch_bounds__(256) void add_offsets(int* __restrict__ a,
                                                   int* __restrict__ cur,
                                                   const int* __restrict__ bsum) {
    __shared__ int off_s;
    const int t = threadIdx.x, b = blockIdx.x;
    if (t == 0) off_s = 0;
    __syncthreads();
    int partial = 0;
    for (int j = t; j < b; j += 256) partial += bsum[j];
#pragma unroll
    for (int off = 32; off >= 1; off >>= 1) partial += __shfl_down(partial, off, 64);
    if ((t & 63) == 0) atomicAdd(&off_s, partial);
    __syncthreads();
    const int off = off_s;
    const int i = b * 256 + t;
    if (i < N_NODES) { const int v = a[i] + off; a[i] = v; cur[i] = v; }
    if (b == gridDim.x - 1 && t == 0) a[N_NODES] = off + bsum[b];
}

// XCD-partitioned fill: partition p = blockIdx%8 handles dst in
// [p*6250, (p+1)*6250) only -> each partition's csr_src writes land in one
// contiguous region owned (heuristically) by one XCD's L2 -> full-line
// write-combining instead of one 64B writeback per 4B store.
__global__ __launch_bounds__(256) void csr_fill_part(const int* __restrict__ eg,
                                                     int* __restrict__ cur,
                                                     int* __restrict__ csr_src) {
    constexpr int PART = N_NODES / 8;  // 6250
    const int part = blockIdx.x & 7;
    const int q = blockIdx.x >> 3;
    const int lo = part * PART;
    const int hi = lo + PART;
    const int stride = (gridDim.x >> 3) * 256;
    for (int e = q * 256 + threadIdx.x; e < N_EDGES; e += stride) {
        const int d = eg[N_EDGES + e];
        if (d >= lo && d < hi) {
            const int p = atomicAdd(&cur[d], 1);
            csr_src[p] = eg[e];
        }
    }
}

// ---------------------------------------------------------------------------
// bf16 MFMA GEMM, 2-phase pipelined (T14): C[MP,BN] = A[MP,K] @ Bt[BN,K]^T.
// BM=64, BK=64, 8 waves (2m x 4n). Reg-staged prefetch; single LDS buffer,
// XOR-swizzled 16B slots. AF32: A f32->bf16 fused. CFP8: C stored fp8 e4m3.
// ---------------------------------------------------------------------------
template <int K, int BN, bool AF32, bool CFP8>
__global__ __launch_bounds__(512) void gemm_mfma(const void* __restrict__ Av,
                                                 const ushort_t* __restrict__ Bt,
                                                 void* __restrict__ Cv) {
    constexpr int KT = K / 64;
    constexpr int NF = BN / 64;               // n-frags per wave
    constexpr int BSL = (BN == 256) ? 4 : 2;  // B slots per thread
    __shared__ ushort_t lA[64 * 64];
    __shared__ ushort_t lB[BN * 64];
    const int tid = threadIdx.x;
    const int w = tid >> 6, lane = tid & 63;
    const int wr = w >> 2, wc = w & 3;
    const int m0 = blockIdx.x * 64;

    const int ar = tid >> 3, aq = tid & 7;
    const int br = (BN == 256) ? (tid >> 1) : (tid >> 2);
    const int bs0 = (BN == 256) ? ((tid & 1) * 4) : ((tid & 3) * 2);

    int agr = m0 + ar;
    if (AF32 && agr >= N_NODES) agr = 0;  // x has exactly N_NODES rows

    f32x4 acc[2][NF];
#pragma unroll
    for (int m = 0; m < 2; ++m)
#pragma unroll
        for (int n = 0; n < NF; ++n) acc[m][n] = (f32x4){0.f, 0.f, 0.f, 0.f};

    float4 rAf0, rAf1;
    int4v rAh;
    int4v rB[BSL];

    auto LOAD = [&](int kt) {
        if constexpr (AF32) {
            const float* Af = (const float*)Av;
            const float4* p = (const float4*)(Af + (size_t)agr * K + kt * 64 + aq * 8);
            rAf0 = p[0];
            rAf1 = p[1];
        } else {
            const ushort_t* Ab = (const ushort_t*)Av;
            rAh = *(const int4v*)(Ab + (size_t)(m0 + ar) * K + kt * 64 + aq * 8);
        }
        const int4v* qp = (const int4v*)(Bt + (size_t)br * K + kt * 64 + bs0 * 8);
#pragma unroll
        for (int s = 0; s < BSL; ++s) rB[s] = qp[s];
    };

    auto STORE = [&]() {
        short8 oa;
        if constexpr (AF32) {
            oa[0] = (short)f2bf(rAf0.x); oa[1] = (short)f2bf(rAf0.y);
            oa[2] = (short)f2bf(rAf0.z); oa[3] = (short)f2bf(rAf0.w);
            oa[4] = (short)f2bf(rAf1.x); oa[5] = (short)f2bf(rAf1.y);
            oa[6] = (short)f2bf(rAf1.z); oa[7] = (short)f2bf(rAf1.w);
        } else {
            __builtin_memcpy(&oa, &rAh, 16);
        }
        *(short8*)((char*)lA + ar * 128 + ((aq ^ (ar & 7)) << 4)) = oa;
#pragma unroll
        for (int s = 0; s < BSL; ++s) {
            short8 ob;
            __builtin_memcpy(&ob, &rB[s], 16);
            *(short8*)((char*)lB + br * 128 + (((bs0 + s) ^ (br & 7)) << 4)) = ob;
        }
    };

    LOAD(0);
    STORE();
    __syncthreads();

    for (int kt = 0; kt < KT; ++kt) {
        if (kt + 1 < KT) LOAD(kt + 1);          // prefetch next tile to regs
        __builtin_amdgcn_sched_barrier(0);      // pin issue before compute
        const int g = lane >> 4, rr = lane & 15;
#pragma unroll
        for (int kk = 0; kk < 2; ++kk) {
            short8 av[2], bv[NF];
#pragma unroll
            for (int m = 0; m < 2; ++m) {
                const int row = wr * 32 + m * 16 + rr;
                av[m] = *(const short8*)((const char*)lA + row * 128 +
                                         (((kk * 4 + g) ^ (row & 7)) << 4));
            }
#pragma unroll
            for (int n = 0; n < NF; ++n) {
                const int row = wc * (BN / 4) + n * 16 + rr;
                bv[n] = *(const short8*)((const char*)lB + row * 128 +
                                         (((kk * 4 + g) ^ (row & 7)) << 4));
            }
#pragma unroll
            for (int m = 0; m < 2; ++m)
#pragma unroll
                for (int n = 0; n < NF; ++n)
                    acc[m][n] = __builtin_amdgcn_mfma_f32_16x16x32_bf16(
                        av[m], bv[n], acc[m][n], 0, 0, 0);
        }
        __syncthreads();
        if (kt + 1 < KT) {
            STORE();  // waits on prefetched loads; latency hidden under MFMA
            __syncthreads();
        }
    }

    const int rr = lane & 15, rg = lane >> 4;
#pragma unroll
    for (int m = 0; m < 2; ++m)
#pragma unroll
        for (int n = 0; n < NF; ++n)
#pragma unroll
            for (int q = 0; q < 4; ++q) {
                const int row = m0 + wr * 32 + m * 16 + rg * 4 + q;
                const int col = wc * (BN / 4) + n * 16 + rr;
                if constexpr (CFP8) {
                    ((unsigned char*)Cv)[(size_t)row * BN + col] =
                        f32_to_fp8(acc[m][n][q]);
                } else {
                    ((ushort_t*)Cv)[(size_t)row * BN + col] = f2bf(acc[m][n][q]);
                }
            }
}

// ---------------------------------------------------------------------------
// Layer-1 gather over fp8 support (row = 256 fp8 = 256B) + bias + ReLU,
// bf16 output. 16 lanes/node, 16 fp8 (16B) per lane per edge, 8-deep chunks.
// ---------------------------------------------------------------------------
template <bool MASKED>
__device__ __forceinline__ void chunk8_fp8(const unsigned char* __restrict__ S,
                                           const int* __restrict__ csr,
                                           int j, int end, int coff,
                                           float* __restrict__ acc) {
    int id[8];
#pragma unroll
    for (int q = 0; q < 8; ++q) id[q] = csr[j + q];
    uint4v v[8];
#pragma unroll
    for (int q = 0; q < 8; ++q)
        v[q] = *(const uint4v*)(S + (size_t)id[q] * 256 + coff);
#pragma unroll
    for (int q = 0; q < 8; ++q) {
        const float mq = MASKED ? ((j + q < end) ? 1.f : 0.f) : 1.f;
#pragma unroll
        for (int wd = 0; wd < 4; ++wd) {
            const uint_t word = v[q][wd];
#pragma unroll
            for (int b = 0; b < 4; ++b) {
                const float f = fp8_to_f32((unsigned char)((word >> (8 * b)) & 0xFF));
                if (MASKED)
                    acc[wd * 4 + b] = fmaf(mq, f, acc[wd * 4 + b]);
                else
                    acc[wd * 4 + b] += f;
            }
        }
    }
}

__global__ __launch_bounds__(256) void gather1_fp8(
    const unsigned char* __restrict__ S, const int* __restrict__ rowptr,
    const int* __restrict__ csr_src, const float* __restrict__ bias,
    ushort_t* __restrict__ out) {
    const int gtid = blockIdx.x * blockDim.x + threadIdx.x;
    const int node = gtid >> 4;
    const int l = gtid & 15;
    if (node >= N_NODES) return;
    const int beg = rowptr[node];
    const int end = rowptr[node + 1];
    const int coff = l * 16;

    float acc[16];
#pragma unroll
    for (int k = 0; k < 16; ++k) acc[k] = 0.f;

    const int deg = end - beg;
    int j = beg;
    const int e8 = beg + (deg & ~7);
    for (; j < e8; j += 8) chunk8_fp8<false>(S, csr_src, j, end, coff, acc);
    if (j < end) chunk8_fp8<true>(S, csr_src, j, end, coff, acc);

#pragma unroll
    for (int k = 0; k < 16; ++k) acc[k] = fmaxf(acc[k] + bias[coff + k], 0.f);

    short8 o0, o1;
#pragma unroll
    for (int k = 0; k < 8; ++k) {
        o0[k] = (short)f2bf(acc[k]);
        o1[k] = (short)f2bf(acc[8 + k]);
    }
    ushort_t* op = out + (size_t)node * 256 + coff;
    *(short8*)(op) = o0;
    *(short8*)(op + 8) = o1;
}

// ---------------------------------------------------------------------------
// Layer-2 gather (bf16 support): full 16-chunks + 8 + masked-8 tail.
// ---------------------------------------------------------------------------
template <int D, int CH, bool MASKED>
__device__ __forceinline__ void chunkN(const ushort_t* __restrict__ S,
                                       const int* __restrict__ csr,
                                       int j, int end, size_t coff,
                                       float* __restrict__ acc) {
    int id[CH];
#pragma unroll
    for (int q = 0; q < CH; ++q) id[q] = csr[j + q];
    short8 v[CH];
#pragma unroll
    for (int q = 0; q < CH; ++q)
        v[q] = *(const short8*)(S + (size_t)id[q] * D + coff);
#pragma unroll
    for (int q = 0; q < CH; ++q) {
        if (MASKED) {
            const float mq = (j + q < end) ? 1.f : 0.f;
#pragma unroll
            for (int k = 0; k < 8; ++k)
                acc[k] = fmaf(mq, bf2f((ushort_t)v[q][k]), acc[k]);
        } else {
#pragma unroll
            for (int k = 0; k < 8; ++k) acc[k] += bf2f((ushort_t)v[q][k]);
        }
    }
}

template <int D, bool OUT_BF16>
__global__ __launch_bounds__(256) void gather_bias_relu(
    const ushort_t* __restrict__ S, const int* __restrict__ rowptr,
    const int* __restrict__ csr_src, const float* __restrict__ bias,
    void* __restrict__ out) {
    constexpr int LPN = D / 8;
    const int gtid = blockIdx.x * blockDim.x + threadIdx.x;
    const int node = gtid / LPN;
    const int l = gtid % LPN;
    if (node >= N_NODES) return;
    const int beg = rowptr[node];
    const int end = rowptr[node + 1];
    const size_t coff = 8 * (size_t)l;

    float acc[8];
#pragma unroll
    for (int k = 0; k < 8; ++k) acc[k] = 0.f;

    const int deg = end - beg;
    int j = beg;
    const int e16 = beg + (deg & ~15);
    for (; j < e16; j += 16) chunkN<D, 16, false>(S, csr_src, j, end, coff, acc);
    if (deg & 8) {
        chunkN<D, 8, false>(S, csr_src, j, end, coff, acc);
        j += 8;
    }
    if (j < end) chunkN<D, 8, true>(S, csr_src, j, end, coff, acc);

#pragma unroll
    for (int k = 0; k < 8; ++k) acc[k] = fmaxf(acc[k] + bias[coff + k], 0.f);

    if (OUT_BF16) {
        short8 o;
#pragma unroll
        for (int k = 0; k < 8; ++k) o[k] = (short)f2bf(acc[k]);
        *(short8*)((ushort_t*)out + (size_t)node * D + coff) = o;
    } else {
        float* op = (float*)out + (size_t)node * D + coff;
        *(float4*)(op + 0) = make_float4(acc[0], acc[1], acc[2], acc[3]);
        *(float4*)(op + 4) = make_float4(acc[4], acc[5], acc[6], acc[7]);
    }
}

// ---------------------------------------------------------------------------
extern "C" void kernel_launch(void* const* d_in, const int* in_sizes, int n_in,
                              void* d_out, int out_size, void* d_ws, size_t ws_size,
                              hipStream_t stream) {
    const float* x  = (const float*)d_in[0];
    const int*   eg = (const int*)d_in[1];
    const float* W1 = (const float*)d_in[2];
    const float* b1 = (const float*)d_in[3];
    const float* W2 = (const float*)d_in[4];
    const float* b2 = (const float*)d_in[5];
    float* out = (float*)d_out;

    char* ws = (char*)d_ws;
    const size_t SUP1_OFF = 0;              // MP*256*1 (fp8) = 12,845,056
    const size_t AGG1_OFF = 25690112;       // MP*256*2 (bf16)
    const size_t SUP2_OFF = 51380224;       // MP*128*2 (bf16)
    const size_t W1T_OFF  = 77070336;       // 262,144
    const size_t W2T_OFF  = 77332480;       // 65,536
    const size_t RP_OFF   = 77398016;       // 50001*4 (pad to 200,016)
    const size_t CUR_OFF  = 77598032;       // 200,000
    const size_t CSR_OFF  = 77798032;       // 800016*4 = 3,200,064
    const size_t BSUM_OFF = 80998096;       // 196*4  (end ~81.0 MB)

    unsigned char* sup1 = (unsigned char*)(ws + SUP1_OFF);
    ushort_t* agg1 = (ushort_t*)(ws + AGG1_OFF);
    ushort_t* sup2 = (ushort_t*)(ws + SUP2_OFF);
    ushort_t* W1t  = (ushort_t*)(ws + W1T_OFF);
    ushort_t* W2t  = (ushort_t*)(ws + W2T_OFF);
    int* rowptr  = (int*)(ws + RP_OFF);
    int* cur     = (int*)(ws + CUR_OFF);
    int* csr_src = (int*)(ws + CSR_OFF);
    int* bsum    = (int*)(ws + BSUM_OFF);

    const int SCAN_BLKS = (N_NODES + 255) / 256;  // 196

    prep<<<512, 256, 0, stream>>>(W1, W2, W1t, W2t, rowptr, csr_src);

    // ---- CSR build ----
    edge_hist<<<(N_EDGES + 255) / 256, 256, 0, stream>>>(eg, rowptr);
    scan_blocks<<<SCAN_BLKS, 256, 0, stream>>>(rowptr, bsum);
    add_offsets<<<SCAN_BLKS, 256, 0, stream>>>(rowptr, cur, bsum);
    csr_fill_part<<<2048, 256, 0, stream>>>(eg, cur, csr_src);

    // ---- layer 1: gemm (A = x f32, fused convert; C = fp8) + fp8 gather ----
    gemm_mfma<512, 256, true, true><<<MP / 64, 512, 0, stream>>>(x, W1t, sup1);
    gather1_fp8<<<(N_NODES * 16 + 255) / 256, 256, 0, stream>>>(
        sup1, rowptr, csr_src, b1, agg1);

    // ---- layer 2 (bf16 throughout) ----
    gemm_mfma<256, 128, false, false><<<MP / 64, 512, 0, stream>>>(agg1, W2t, sup2);
    gather_bias_relu<128, false><<<(N_NODES * 16 + 255) / 256, 256, 0, stream>>>(
        sup2, rowptr, csr_src, b2, out);
}

// Round 9
// 193.780 us; speedup vs baseline: 22.6316x; 1.0507x over previous
//
#include <hip/hip_runtime.h>
#include <hip/hip_fp8.h>

#define N_NODES 50000
#define N_EDGES 800000
#define MP 50176  // 392 * 128, padded M for GEMM tiles

typedef unsigned short ushort_t;
typedef unsigned int uint_t;
using short8 = __attribute__((ext_vector_type(8))) short;
using f32x4 = __attribute__((ext_vector_type(4))) float;
using int4v = __attribute__((ext_vector_type(4))) int;
using uint4v = __attribute__((ext_vector_type(4))) uint_t;

__device__ __forceinline__ ushort_t f2bf(float f) {
    uint_t u;
    __builtin_memcpy(&u, &f, 4);
    u = u + 0x7FFF + ((u >> 16) & 1);  // RNE
    return (ushort_t)(u >> 16);
}

__device__ __forceinline__ float bf2f(ushort_t h) {
    uint_t u = ((uint_t)h) << 16;
    float f;
    __builtin_memcpy(&f, &u, 4);
    return f;
}

__device__ __forceinline__ float fp8_to_f32(unsigned char b) {
    const __hip_fp8_e4m3 h = __builtin_bit_cast(__hip_fp8_e4m3, b);
    return (float)h;
}

__device__ __forceinline__ unsigned char f32_to_fp8(float v) {
    return (unsigned char)__hip_fp8_e4m3(v).__x;
}

// ---------------------------------------------------------------------------
// prep: zero rowptr + pad csr_src + transpose both W to bf16.
// ---------------------------------------------------------------------------
__global__ __launch_bounds__(256) void prep(const float* __restrict__ W1,
                                            const float* __restrict__ W2,
                                            ushort_t* __restrict__ W1t,
                                            ushort_t* __restrict__ W2t,
                                            int* __restrict__ rowptr,
                                            int* __restrict__ csr_src) {
    const int i = blockIdx.x * blockDim.x + threadIdx.x;
    if (i < 256 * 512) {               // W1t[n][k] = W1[k][n]
        const int n = i >> 9, k = i & 511;
        W1t[i] = f2bf(W1[(size_t)k * 256 + n]);
    }
    if (i < 128 * 256) {               // W2t[n][k] = W2[k][n]
        const int n = i >> 8, k = i & 255;
        W2t[i] = f2bf(W2[(size_t)k * 128 + n]);
    }
    if (i <= N_NODES) rowptr[i] = 0;
    if (i < 16) csr_src[N_EDGES + i] = 0;  // safe pad for masked gather chunks
}

// ---------------------------------------------------------------------------
// CSR build: hist -> per-block scan -> add block offsets -> fill (fat kernel).
// ---------------------------------------------------------------------------
__global__ void edge_hist(const int* __restrict__ eg, int* __restrict__ cnt) {
    const int e = blockIdx.x * blockDim.x + threadIdx.x;
    if (e >= N_EDGES) return;
    atomicAdd(&cnt[eg[N_EDGES + e]], 1);
}

__global__ __launch_bounds__(256) void scan_blocks(int* __restrict__ a,
                                                   int* __restrict__ bsum) {
    __shared__ int wsum[4];
    const int t = threadIdx.x, lane = t & 63, wid = t >> 6;
    const int i = blockIdx.x * 256 + t;
    const int v = (i < N_NODES) ? a[i] : 0;
    int s = v;
#pragma unroll
    for (int off = 1; off < 64; off <<= 1) {
        const int u = __shfl_up(s, off, 64);
        if (lane >= off) s += u;
    }
    if (lane == 63) wsum[wid] = s;
    __syncthreads();
    if (t == 0) {
        const int a0 = wsum[0], a1 = wsum[1], a2 = wsum[2], a3 = wsum[3];
        wsum[0] = 0; wsum[1] = a0; wsum[2] = a0 + a1; wsum[3] = a0 + a1 + a2;
        bsum[blockIdx.x] = a0 + a1 + a2 + a3;
    }
    __syncthreads();
    if (i < N_NODES) a[i] = wsum[wid] + s - v;
}

__global__ __launch_bounds__(256) void add_offsets(int* __restrict__ a,
                                                   int* __restrict__ cur,
                                                   const int* __restrict__ bsum) {
    __shared__ int off_s;
    const int t = threadIdx.x, b = blockIdx.x;
    if (t == 0) off_s = 0;
    __syncthreads();
    int partial = 0;
    for (int j = t; j < b; j += 256) partial += bsum[j];
#pragma unroll
    for (int off = 32; off >= 1; off >>= 1) partial += __shfl_down(partial, off, 64);
    if ((t & 63) == 0) atomicAdd(&off_s, partial);
    __syncthreads();
    const int off = off_s;
    const int i = b * 256 + t;
    if (i < N_NODES) { const int v = a[i] + off; a[i] = v; cur[i] = v; }
    if (b == gridDim.x - 1 && t == 0) a[N_NODES] = off + bsum[b];
}

// ---------------------------------------------------------------------------
// bf16 MFMA GEMM body (device fn), 2-phase pipelined (T14).
// BM=64, BK=64, 8 waves (2m x 4n). Reg-staged prefetch; single LDS buffer,
// XOR-swizzled 16B slots. AF32: A f32->bf16 fused. CFP8: C stored fp8 e4m3.
// ---------------------------------------------------------------------------
template <int K, int BN, bool AF32, bool CFP8>
__device__ __forceinline__ void gemm_body(const void* __restrict__ Av,
                                          const ushort_t* __restrict__ Bt,
                                          void* __restrict__ Cv, int bidx) {
    constexpr int KT = K / 64;
    constexpr int NF = BN / 64;
    constexpr int BSL = (BN == 256) ? 4 : 2;
    __shared__ ushort_t lA[64 * 64];
    __shared__ ushort_t lB[BN * 64];
    const int tid = threadIdx.x;
    const int w = tid >> 6, lane = tid & 63;
    const int wr = w >> 2, wc = w & 3;
    const int m0 = bidx * 64;

    const int ar = tid >> 3, aq = tid & 7;
    const int br = (BN == 256) ? (tid >> 1) : (tid >> 2);
    const int bs0 = (BN == 256) ? ((tid & 1) * 4) : ((tid & 3) * 2);

    int agr = m0 + ar;
    if (AF32 && agr >= N_NODES) agr = 0;  // x has exactly N_NODES rows

    f32x4 acc[2][NF];
#pragma unroll
    for (int m = 0; m < 2; ++m)
#pragma unroll
        for (int n = 0; n < NF; ++n) acc[m][n] = (f32x4){0.f, 0.f, 0.f, 0.f};

    float4 rAf0, rAf1;
    int4v rAh;
    int4v rB[BSL];

    auto LOAD = [&](int kt) {
        if constexpr (AF32) {
            const float* Af = (const float*)Av;
            const float4* p = (const float4*)(Af + (size_t)agr * K + kt * 64 + aq * 8);
            rAf0 = p[0];
            rAf1 = p[1];
        } else {
            const ushort_t* Ab = (const ushort_t*)Av;
            rAh = *(const int4v*)(Ab + (size_t)(m0 + ar) * K + kt * 64 + aq * 8);
        }
        const int4v* qp = (const int4v*)(Bt + (size_t)br * K + kt * 64 + bs0 * 8);
#pragma unroll
        for (int s = 0; s < BSL; ++s) rB[s] = qp[s];
    };

    auto STORE = [&]() {
        short8 oa;
        if constexpr (AF32) {
            oa[0] = (short)f2bf(rAf0.x); oa[1] = (short)f2bf(rAf0.y);
            oa[2] = (short)f2bf(rAf0.z); oa[3] = (short)f2bf(rAf0.w);
            oa[4] = (short)f2bf(rAf1.x); oa[5] = (short)f2bf(rAf1.y);
            oa[6] = (short)f2bf(rAf1.z); oa[7] = (short)f2bf(rAf1.w);
        } else {
            __builtin_memcpy(&oa, &rAh, 16);
        }
        *(short8*)((char*)lA + ar * 128 + ((aq ^ (ar & 7)) << 4)) = oa;
#pragma unroll
        for (int s = 0; s < BSL; ++s) {
            short8 ob;
            __builtin_memcpy(&ob, &rB[s], 16);
            *(short8*)((char*)lB + br * 128 + (((bs0 + s) ^ (br & 7)) << 4)) = ob;
        }
    };

    LOAD(0);
    STORE();
    __syncthreads();

    for (int kt = 0; kt < KT; ++kt) {
        if (kt + 1 < KT) LOAD(kt + 1);          // prefetch next tile to regs
        __builtin_amdgcn_sched_barrier(0);      // pin issue before compute
        const int g = lane >> 4, rr = lane & 15;
#pragma unroll
        for (int kk = 0; kk < 2; ++kk) {
            short8 av[2], bv[NF];
#pragma unroll
            for (int m = 0; m < 2; ++m) {
                const int row = wr * 32 + m * 16 + rr;
                av[m] = *(const short8*)((const char*)lA + row * 128 +
                                         (((kk * 4 + g) ^ (row & 7)) << 4));
            }
#pragma unroll
            for (int n = 0; n < NF; ++n) {
                const int row = wc * (BN / 4) + n * 16 + rr;
                bv[n] = *(const short8*)((const char*)lB + row * 128 +
                                         (((kk * 4 + g) ^ (row & 7)) << 4));
            }
#pragma unroll
            for (int m = 0; m < 2; ++m)
#pragma unroll
                for (int n = 0; n < NF; ++n)
                    acc[m][n] = __builtin_amdgcn_mfma_f32_16x16x32_bf16(
                        av[m], bv[n], acc[m][n], 0, 0, 0);
        }
        __syncthreads();
        if (kt + 1 < KT) {
            STORE();  // waits on prefetched loads; latency hidden under MFMA
            __syncthreads();
        }
    }

    const int rr = lane & 15, rg = lane >> 4;
#pragma unroll
    for (int m = 0; m < 2; ++m)
#pragma unroll
        for (int n = 0; n < NF; ++n)
#pragma unroll
            for (int q = 0; q < 4; ++q) {
                const int row = m0 + wr * 32 + m * 16 + rg * 4 + q;
                const int col = wc * (BN / 4) + n * 16 + rr;
                if constexpr (CFP8) {
                    ((unsigned char*)Cv)[(size_t)row * BN + col] =
                        f32_to_fp8(acc[m][n][q]);
                } else {
                    ((ushort_t*)Cv)[(size_t)row * BN + col] = f2bf(acc[m][n][q]);
                }
            }
}

// ---------------------------------------------------------------------------
// Fat kernel: blocks [0, GB) run gemm1; blocks [GB, GB+FB) run the
// XCD-partitioned csr fill (independent work, overlapped on the machine).
// Fill partition p handles dst in [p*6250,(p+1)*6250) -> contiguous csr_src
// region -> full-line write combining (R7 win, 512-thread variant).
// ---------------------------------------------------------------------------
#define GEMM1_BLOCKS (MP / 64)   // 784
#define FILL_BLOCKS  1024

__global__ __launch_bounds__(512) void gemm1_fill(
    const float* __restrict__ x, const ushort_t* __restrict__ W1t,
    unsigned char* __restrict__ sup1, const int* __restrict__ eg,
    int* __restrict__ cur, int* __restrict__ csr_src) {
    if (blockIdx.x < GEMM1_BLOCKS) {
        gemm_body<512, 256, true, true>(x, W1t, sup1, blockIdx.x);
    } else {
        constexpr int PART = N_NODES / 8;  // 6250
        const int fb = blockIdx.x - GEMM1_BLOCKS;
        const int part = fb & 7;
        const int q = fb >> 3;
        const int lo = part * PART;
        const int hi = lo + PART;
        const int stride = (FILL_BLOCKS >> 3) * 512;
        for (int e = q * 512 + threadIdx.x; e < N_EDGES; e += stride) {
            const int d = eg[N_EDGES + e];
            if (d >= lo && d < hi) {
                const int p = atomicAdd(&cur[d], 1);
                csr_src[p] = eg[e];
            }
        }
    }
}

__global__ __launch_bounds__(512) void gemm2_k(const ushort_t* __restrict__ A,
                                               const ushort_t* __restrict__ Bt,
                                               unsigned char* __restrict__ C) {
    gemm_body<256, 128, false, true>(A, Bt, C, blockIdx.x);
}

// ---------------------------------------------------------------------------
// fp8 gather + bias + ReLU. Row = D fp8 bytes; D/16 lanes per node,
// 16 fp8 (16B) per lane per edge, 8-deep chunks. OUT_BF16 -> bf16, else f32.
// ---------------------------------------------------------------------------
template <int D, bool MASKED>
__device__ __forceinline__ void chunk8_fp8(const unsigned char* __restrict__ S,
                                           const int* __restrict__ csr,
                                           int j, int end, int coff,
                                           float* __restrict__ acc) {
    int id[8];
#pragma unroll
    for (int q = 0; q < 8; ++q) id[q] = csr[j + q];
    uint4v v[8];
#pragma unroll
    for (int q = 0; q < 8; ++q)
        v[q] = *(const uint4v*)(S + (size_t)id[q] * D + coff);
#pragma unroll
    for (int q = 0; q < 8; ++q) {
        const float mq = MASKED ? ((j + q < end) ? 1.f : 0.f) : 1.f;
#pragma unroll
        for (int wd = 0; wd < 4; ++wd) {
            const uint_t word = v[q][wd];
#pragma unroll
            for (int b = 0; b < 4; ++b) {
                const float f = fp8_to_f32((unsigned char)((word >> (8 * b)) & 0xFF));
                if (MASKED)
                    acc[wd * 4 + b] = fmaf(mq, f, acc[wd * 4 + b]);
                else
                    acc[wd * 4 + b] += f;
            }
        }
    }
}

template <int D, bool OUT_BF16>
__global__ __launch_bounds__(256) void gather_fp8(
    const unsigned char* __restrict__ S, const int* __restrict__ rowptr,
    const int* __restrict__ csr_src, const float* __restrict__ bias,
    void* __restrict__ out) {
    constexpr int LPN = D / 16;
    const int gtid = blockIdx.x * blockDim.x + threadIdx.x;
    const int node = gtid / LPN;
    const int l = gtid % LPN;
    if (node >= N_NODES) return;
    const int beg = rowptr[node];
    const int end = rowptr[node + 1];
    const int coff = l * 16;

    float acc[16];
#pragma unroll
    for (int k = 0; k < 16; ++k) acc[k] = 0.f;

    const int deg = end - beg;
    int j = beg;
    const int e8 = beg + (deg & ~7);
    for (; j < e8; j += 8) chunk8_fp8<D, false>(S, csr_src, j, end, coff, acc);
    if (j < end) chunk8_fp8<D, true>(S, csr_src, j, end, coff, acc);

#pragma unroll
    for (int k = 0; k < 16; ++k) acc[k] = fmaxf(acc[k] + bias[coff + k], 0.f);

    if (OUT_BF16) {
        short8 o0, o1;
#pragma unroll
        for (int k = 0; k < 8; ++k) {
            o0[k] = (short)f2bf(acc[k]);
            o1[k] = (short)f2bf(acc[8 + k]);
        }
        ushort_t* op = (ushort_t*)out + (size_t)node * D + coff;
        *(short8*)(op) = o0;
        *(short8*)(op + 8) = o1;
    } else {
        float* op = (float*)out + (size_t)node * D + coff;
        *(float4*)(op + 0)  = make_float4(acc[0], acc[1], acc[2], acc[3]);
        *(float4*)(op + 4)  = make_float4(acc[4], acc[5], acc[6], acc[7]);
        *(float4*)(op + 8)  = make_float4(acc[8], acc[9], acc[10], acc[11]);
        *(float4*)(op + 12) = make_float4(acc[12], acc[13], acc[14], acc[15]);
    }
}

// ---------------------------------------------------------------------------
extern "C" void kernel_launch(void* const* d_in, const int* in_sizes, int n_in,
                              void* d_out, int out_size, void* d_ws, size_t ws_size,
                              hipStream_t stream) {
    const float* x  = (const float*)d_in[0];
    const int*   eg = (const int*)d_in[1];
    const float* W1 = (const float*)d_in[2];
    const float* b1 = (const float*)d_in[3];
    const float* W2 = (const float*)d_in[4];
    const float* b2 = (const float*)d_in[5];
    float* out = (float*)d_out;

    char* ws = (char*)d_ws;
    const size_t SUP1_OFF = 0;              // MP*256 fp8 = 12,845,056
    const size_t AGG1_OFF = 25690112;       // MP*256*2 (bf16)
    const size_t SUP2_OFF = 51380224;       // MP*128 fp8 = 6,422,528
    const size_t W1T_OFF  = 77070336;       // 262,144
    const size_t W2T_OFF  = 77332480;       // 65,536
    const size_t RP_OFF   = 77398016;       // 50001*4 (pad to 200,016)
    const size_t CUR_OFF  = 77598032;       // 200,000
    const size_t CSR_OFF  = 77798032;       // 800016*4 = 3,200,064
    const size_t BSUM_OFF = 80998096;       // 196*4  (end ~81.0 MB)

    unsigned char* sup1 = (unsigned char*)(ws + SUP1_OFF);
    ushort_t* agg1 = (ushort_t*)(ws + AGG1_OFF);
    unsigned char* sup2 = (unsigned char*)(ws + SUP2_OFF);
    ushort_t* W1t  = (ushort_t*)(ws + W1T_OFF);
    ushort_t* W2t  = (ushort_t*)(ws + W2T_OFF);
    int* rowptr  = (int*)(ws + RP_OFF);
    int* cur     = (int*)(ws + CUR_OFF);
    int* csr_src = (int*)(ws + CSR_OFF);
    int* bsum    = (int*)(ws + BSUM_OFF);

    const int SCAN_BLKS = (N_NODES + 255) / 256;  // 196

    prep<<<512, 256, 0, stream>>>(W1, W2, W1t, W2t, rowptr, csr_src);

    // ---- CSR build (fill overlapped with gemm1 below) ----
    edge_hist<<<(N_EDGES + 255) / 256, 256, 0, stream>>>(eg, rowptr);
    scan_blocks<<<SCAN_BLKS, 256, 0, stream>>>(rowptr, bsum);
    add_offsets<<<SCAN_BLKS, 256, 0, stream>>>(rowptr, cur, bsum);

    // ---- layer 1 gemm (fused f32->bf16, fp8 C) || csr fill ----
    gemm1_fill<<<GEMM1_BLOCKS + FILL_BLOCKS, 512, 0, stream>>>(
        x, W1t, sup1, eg, cur, csr_src);
    gather_fp8<256, true><<<(N_NODES * 16 + 255) / 256, 256, 0, stream>>>(
        sup1, rowptr, csr_src, b1, agg1);

    // ---- layer 2 (fp8 support) ----
    gemm2_k<<<MP / 64, 512, 0, stream>>>(agg1, W2t, sup2);
    gather_fp8<128, false><<<(N_NODES * 8 + 255) / 256, 256, 0, stream>>>(
        sup2, rowptr, csr_src, b2, out);
}